// Round 3
// baseline (560.829 us; speedup 1.0000x reference)
//
#include <hip/hip_runtime.h>
#include <hip/hip_bf16.h>
#include <math.h>

using bf16 = __hip_bfloat16;
typedef __attribute__((ext_vector_type(8))) short short8;
typedef __attribute__((ext_vector_type(4))) float f32x4;

static constexpr int B_ = 4, C_ = 512, L_ = 4096, M_ = 16384;
static constexpr size_t MB = 1ull << 20;

__device__ __forceinline__ float b2f(bf16 v){ return __bfloat162float(v); }
__device__ __forceinline__ bf16  f2b(float v){ return __float2bfloat16(v); }

// async global -> LDS, 16B per lane, lane l lands at (wave-uniform base) + l*16
__device__ __forceinline__ void gl_lds16(const bf16* g, bf16* l) {
  __builtin_amdgcn_global_load_lds(
      (const __attribute__((address_space(1))) unsigned int*)g,
      (__attribute__((address_space(3))) unsigned int*)l, 16, 0, 0);
}

// gelu(g) = 0.5 g (1 + erf(g/sqrt2)); erf via A&S 7.1.26 (|eps| < 1.5e-7)
__device__ __forceinline__ float fast_gelu(float g) {
  float t  = g * 0.70710678118654752f;
  float at = fabsf(t);
  float k  = 1.f / (1.f + 0.3275911f * at);
  float poly = k * (0.254829592f + k * (-0.284496736f + k * (1.421413741f +
               k * (-1.453152027f + k * 1.061405429f))));
  float erfv = 1.f - poly * __expf(-at * at);
  erfv = __builtin_copysignf(erfv, t);
  return 0.5f * g * (1.f + erfv);
}

// ---------------- fused weight transpose: 11 jobs in one dispatch ----------
// mode a==1: dst row = n + b.  mode a==2: granule-16 geglu interleave:
//   dst row = ((n>>4)<<5) + b*16 + (n&15)   (b=0: a-half, b=1: gate-half)
struct TransJobs {
  const float* src[11];
  bf16* dst[11];
  int K[11], N[11], srcStride[11], srcColOff[11], a[11], b[11];
  int tileStart[12];
};

__global__ __launch_bounds__(256) void transpose_all(TransJobs J)
{
  __shared__ float tile[32][33];
  int t = blockIdx.x;
  int j = 0;
  #pragma unroll
  for (int q = 0; q < 10; q++) if (t >= J.tileStart[q + 1]) j = q + 1;
  t -= J.tileStart[j];
  const int kTiles = J.K[j] >> 5;
  const int k0 = (t % kTiles) * 32, n0 = (t / kTiles) * 32;
  const int tx = threadIdx.x, ty = threadIdx.y;
  const float* src = J.src[j];
  const int N = J.N[j], ss = J.srcStride[j], sc = J.srcColOff[j];
  #pragma unroll
  for (int i = 0; i < 32; i += 8) {
    int k = k0 + ty + i, n = n0 + tx;
    tile[ty + i][tx] = (n < N) ? src[(size_t)k * ss + sc + n] : 0.f;
  }
  __syncthreads();
  bf16* dst = J.dst[j];
  const int a = J.a[j], b = J.b[j], K = J.K[j];
  #pragma unroll
  for (int i = 0; i < 32; i += 8) {
    int n = n0 + ty + i, k = k0 + tx;
    int row = (a == 2) ? (((n >> 4) << 5) + b * 16 + (n & 15)) : (n + b);
    dst[(size_t)row * K + k] = f2b(tile[tx][ty + i]);
  }
}

// combined bias [vproj(512) | soff(128) | attw(64) | zero(64)]
__global__ void pack_bias_big(const float* __restrict__ vb,
    const float* __restrict__ sb, const float* __restrict__ ab,
    float* __restrict__ bp){
  int i = blockIdx.x * 256 + threadIdx.x;   // 768 threads
  float v = 0.f;
  if (i < 512) v = vb[i];
  else if (i < 640) v = sb[i - 512];
  else if (i < 704) v = ab[i - 640];
  bp[i] = v;
}

// ---------------- GroupNorm stats (sum, sumsq per (b,g)) ----------------
__global__ __launch_bounds__(256) void gn_partial(const float* __restrict__ x,
                                                  float* __restrict__ stats)
{
  int bg = blockIdx.x >> 4;
  int sc = blockIdx.x & 15;
  size_t base = (size_t)bg * 262144 + (size_t)sc * 16384;
  int tid = threadIdx.x;
  float s = 0.f, s2 = 0.f;
  #pragma unroll
  for (int i = 0; i < 8; i++) {
    size_t o = base + ((size_t)i * 256 + tid) * 8;
    float4 a = *reinterpret_cast<const float4*>(&x[o]);
    float4 b = *reinterpret_cast<const float4*>(&x[o + 4]);
    s  += a.x + a.y + a.z + a.w + b.x + b.y + b.z + b.w;
    s2 += a.x*a.x + a.y*a.y + a.z*a.z + a.w*a.w
        + b.x*b.x + b.y*b.y + b.z*b.z + b.w*b.w;
  }
  #pragma unroll
  for (int o = 32; o; o >>= 1) { s += __shfl_xor(s, o, 64); s2 += __shfl_xor(s2, o, 64); }
  __shared__ float ls[4], ls2[4];
  int wave = tid >> 6, lane = tid & 63;
  if (lane == 0) { ls[wave] = s; ls2[wave] = s2; }
  __syncthreads();
  if (tid == 0) {
    atomicAdd(&stats[bg * 2 + 0], ls[0] + ls[1] + ls[2] + ls[3]);
    atomicAdd(&stats[bg * 2 + 1], ls2[0] + ls2[1] + ls2[2] + ls2[3]);
  }
}

// ---------------- GN apply + transpose (B,C,L) -> (B*L, C) bf16 ----------
__global__ __launch_bounds__(256) void gn_apply_t(const float* __restrict__ x,
    const float* __restrict__ stats, const float* __restrict__ gg,
    const float* __restrict__ gb, bf16* __restrict__ xnt)
{
  __shared__ float tile[32][33];
  int b = blockIdx.z, c0 = blockIdx.y * 32, l0 = blockIdx.x * 32;
  int tx = threadIdx.x, ty = threadIdx.y;
  #pragma unroll
  for (int i = 0; i < 32; i += 8) {
    int c = c0 + ty + i, l = l0 + tx;
    int grp = b * 8 + (c >> 6);
    float sum = stats[grp * 2], ss = stats[grp * 2 + 1];
    float mu = sum * (1.f / 262144.f);
    float inv = rsqrtf(ss * (1.f / 262144.f) - mu * mu + 1e-5f);
    float v = x[((size_t)b * 512 + c) * 4096 + l];
    tile[ty + i][tx] = (v - mu) * inv * gg[c] + gb[c];
  }
  __syncthreads();
  #pragma unroll
  for (int i = 0; i < 32; i += 8) {
    int l = l0 + ty + i, c = c0 + tx;
    xnt[((size_t)b * 4096 + l) * 512 + c] = f2b(tile[tx][ty + i]);
  }
}

// ---------------- LayerNorm over C=512: fp32 in, bf16 out, 1 wave/row -----
__global__ __launch_bounds__(256) void layernorm_k(const float* __restrict__ X,
    const float* __restrict__ g, const float* __restrict__ b, bf16* __restrict__ Y)
{
  int row = blockIdx.x * 4 + (threadIdx.x >> 6);
  int lane = threadIdx.x & 63;
  const float* xr = X + (size_t)row * 512 + lane * 8;
  float4 a = *reinterpret_cast<const float4*>(xr);
  float4 c = *reinterpret_cast<const float4*>(xr + 4);
  float v[8] = {a.x, a.y, a.z, a.w, c.x, c.y, c.z, c.w};
  float s = 0.f, s2 = 0.f;
  #pragma unroll
  for (int i = 0; i < 8; i++) { s += v[i]; s2 += v[i] * v[i]; }
  #pragma unroll
  for (int o = 32; o; o >>= 1) { s += __shfl_xor(s, o, 64); s2 += __shfl_xor(s2, o, 64); }
  float mu = s * (1.f / 512.f);
  float inv = rsqrtf(s2 * (1.f / 512.f) - mu * mu + 1e-5f);
  float4 g0 = *reinterpret_cast<const float4*>(&g[lane * 8]);
  float4 g1 = *reinterpret_cast<const float4*>(&g[lane * 8 + 4]);
  float4 b0 = *reinterpret_cast<const float4*>(&b[lane * 8]);
  float4 b1 = *reinterpret_cast<const float4*>(&b[lane * 8 + 4]);
  float gv[8] = {g0.x, g0.y, g0.z, g0.w, g1.x, g1.y, g1.z, g1.w};
  float bv[8] = {b0.x, b0.y, b0.z, b0.w, b1.x, b1.y, b1.z, b1.w};
  bf16 outv[8];
  #pragma unroll
  for (int i = 0; i < 8; i++) outv[i] = f2b((v[i] - mu) * inv * gv[i] + bv[i]);
  *reinterpret_cast<uint4*>(Y + (size_t)row * 512 + lane * 8) =
      *reinterpret_cast<const uint4*>(outv);
}

// --- MFMA GEMM, 128x128 tile, 512 threads (8 waves, 2x4 frags/wave) -------
// BK=64 full-line staging + XOR swizzle, dbuf. LDS 64 KB -> 2 blocks/CU,
// 16 waves/CU = 4 waves/SIMD (TLP to hide ds_read latency + barrier drain).
// EPI: 0 none | 1 += res[idx] | 3 transpose+residual fp32 out
// EPI 4: n0<512 -> bf16 Cv[m*512+n]; n0>=512 -> fp32 out2[m*256+n-512]
template<typename TOUT, typename TRES, int EPI>
__global__ __launch_bounds__(512) void gemm_bt(const bf16* __restrict__ A,
    const bf16* __restrict__ Bt, const float* __restrict__ bias,
    const TRES* __restrict__ res, TOUT* __restrict__ Cv,
    float* __restrict__ out2, int M, int N, int K)
{
  __shared__ alignas(16) bf16 As[2][128 * 64];
  __shared__ alignas(16) bf16 Bs[2][128 * 64];
  const int tid = threadIdx.x;
  const int m0 = blockIdx.y * 128;
  const int n0 = blockIdx.x * 128;
  const int lane = tid & 63;
  const int wave = tid >> 6;            // 0..7
  const int wm = (wave & 3) * 32;       // 4 m-strips of 32 rows
  const int wn = (wave >> 2) * 64;      // 2 n-strips of 64 cols
  const int fr = lane & 15;
  const int fq = lane >> 4;
  const int sr8 = lane >> 3;                    // row within 8-row staging group
  const int sgl = ((lane & 7) ^ sr8) * 8;       // swizzled source granule (elems)

  const bf16* gaBase = A  + (size_t)(m0 + wave * 16 + sr8) * K + sgl;
  const bf16* gbBase = Bt + (size_t)(n0 + wave * 16 + sr8) * K + sgl;

  f32x4 acc[2][4];
  #pragma unroll
  for (int i = 0; i < 2; i++)
    #pragma unroll
    for (int j = 0; j < 4; j++) acc[i][j] = (f32x4){0.f, 0.f, 0.f, 0.f};

  auto stage = [&](int buf, int kt) {
    const bf16* ga = gaBase + kt;
    const bf16* gb = gbBase + kt;
    bf16* la = &As[buf][wave * 16 * 64];
    bf16* lb = &Bs[buf][wave * 16 * 64];
    gl_lds16(ga, la);                    gl_lds16(ga + (size_t)8 * K, la + 8 * 64);
    gl_lds16(gb, lb);                    gl_lds16(gb + (size_t)8 * K, lb + 8 * 64);
  };

  stage(0, 0);
  int cur = 0;
  for (int kt = 0; kt < K; kt += 64) {
    __syncthreads();                            // drains stage(cur)
    if (kt + 64 < K) stage(cur ^ 1, kt + 64);   // async prefetch next tile
    #pragma unroll
    for (int ko = 0; ko < 2; ko++) {
      const int pa = ((ko * 4 + fq) ^ (fr & 7)) * 8;
      short8 af[2], bfv[4];
      #pragma unroll
      for (int mi = 0; mi < 2; mi++)
        af[mi] = *reinterpret_cast<const short8*>(&As[cur][(wm + mi * 16 + fr) * 64 + pa]);
      #pragma unroll
      for (int ni = 0; ni < 4; ni++)
        bfv[ni] = *reinterpret_cast<const short8*>(&Bs[cur][(wn + ni * 16 + fr) * 64 + pa]);
      #pragma unroll
      for (int mi = 0; mi < 2; mi++)
        #pragma unroll
        for (int ni = 0; ni < 4; ni++)
          acc[mi][ni] = __builtin_amdgcn_mfma_f32_16x16x32_bf16(af[mi], bfv[ni],
                                                                acc[mi][ni], 0, 0, 0);
    }
    cur ^= 1;
  }

  // epilogue: C/D layout col = lane&15, row = (lane>>4)*4 + reg
  #pragma unroll
  for (int ni = 0; ni < 4; ni++) {
    int n = n0 + wn + ni * 16 + fr;
    float bv = bias[n];
    #pragma unroll
    for (int mi = 0; mi < 2; mi++) {
      int mbase = m0 + wm + mi * 16 + fq * 4;
      if (EPI == 3) {
        int b = mbase >> 12, l = mbase & 4095;
        size_t o = ((size_t)(b * 512 + n) << 12) + l;
        float4 xr = *reinterpret_cast<const float4*>(&((const float*)res)[o]);
        float4 vv;
        vv.x = acc[mi][ni][0] + bv + xr.x;
        vv.y = acc[mi][ni][1] + bv + xr.y;
        vv.z = acc[mi][ni][2] + bv + xr.z;
        vv.w = acc[mi][ni][3] + bv + xr.w;
        *reinterpret_cast<float4*>(&((float*)Cv)[o]) = vv;
      } else if (EPI == 4) {
        #pragma unroll
        for (int r = 0; r < 4; r++) {
          float v = acc[mi][ni][r] + bv;
          if (n0 < 512) ((bf16*)Cv)[(size_t)(mbase + r) * 512 + n] = f2b(v);
          else          out2[(size_t)(mbase + r) * 256 + (n - 512)] = v;
        }
      } else {
        #pragma unroll
        for (int r = 0; r < 4; r++) {
          size_t idx = (size_t)(mbase + r) * N + n;
          float v = acc[mi][ni][r] + bv;
          if (EPI == 1) {
            float rv;
            if constexpr (sizeof(TRES) == 2) rv = b2f(((const bf16*)res)[idx]);
            else                             rv = ((const float*)res)[idx];
            v += rv;
          }
          if constexpr (sizeof(TOUT) == 2) ((bf16*)Cv)[idx] = f2b(v);
          else                             ((float*)Cv)[idx] = v;
        }
      }
    }
  }
}

// ====================== GEGLU GEMM — persistent 256x256, 4-phase =========
// Round-2 change: PERSISTENT blocks. Grid 256 (1 block/CU, single round, no
// tail). Each block keeps one 256-row m-panel (A addresses tile-invariant)
// and sweeps 4 n-tiles; the K-stream is continuous: the last iteration of
// tile t stages tile t+1's first A/B into exactly the slots the steady
// state expects, so the pipeline never drains across the whole kernel.
// vmcnt(4) accounting is identical to the verified r2 schedule (same
// 4-loads-per-stage-pair counts; only addresses change). Epilogue VALU and
// stores overlap the next tile's in-flight staging.
#define GG_BAR() __builtin_amdgcn_s_barrier()
#define GG_LG0() do { asm volatile("s_waitcnt lgkmcnt(0)" ::: "memory"); \
                      __builtin_amdgcn_sched_barrier(0); } while (0)
#define GG_VM4() do { asm volatile("s_waitcnt vmcnt(4)" ::: "memory"); \
                      __builtin_amdgcn_sched_barrier(0); } while (0)

#define GG_READ_A(BUF, S)                                                      \
  {                                                                            \
    _Pragma("unroll") for (int mi = 0; mi < 2; mi++)                           \
      _Pragma("unroll") for (int ko = 0; ko < 2; ko++) {                       \
        const int row = wm * 128 + ((S) * 2 + mi) * 16 + fr;                   \
        const int pa = ((ko * 4 + fq) ^ (fr & 7)) * 8;                         \
        af[mi][ko] = *reinterpret_cast<const short8*>(&As[BUF][row * 64 + pa]);\
      }                                                                        \
  }

#define GG_READ_B(BUF)                                                         \
  {                                                                            \
    _Pragma("unroll") for (int ni = 0; ni < 4; ni++)                           \
      _Pragma("unroll") for (int ko = 0; ko < 2; ko++) {                       \
        const int row = wn + ni * 16 + fr;                                     \
        const int pa = ((ko * 4 + fq) ^ (fr & 7)) * 8;                         \
        bfv[ni][ko] = *reinterpret_cast<const short8*>(&Bs[BUF][row * 64 + pa]); \
      }                                                                        \
  }

#define GG_MFMA(S)                                                             \
  __builtin_amdgcn_s_setprio(1);                                               \
  _Pragma("unroll") for (int mi = 0; mi < 2; mi++)                             \
    _Pragma("unroll") for (int ni = 0; ni < 4; ni++)                           \
      _Pragma("unroll") for (int ko = 0; ko < 2; ko++)                         \
        acc[(S) * 2 + mi][ni] = __builtin_amdgcn_mfma_f32_16x16x32_bf16(       \
            af[mi][ko], bfv[ni][ko], acc[(S) * 2 + mi][ni], 0, 0, 0);          \
  __builtin_amdgcn_s_setprio(0);

// one barrier-pair phase: strips S0,S0+1 of buf BUF; STAGE issued pre-bar
#define GG_PHASE(BUF, S0, STAGE_CODE, DO_VM)                                   \
  GG_READ_A(BUF, S0);                                                          \
  if ((S0) == 0) { GG_READ_B(BUF); }                                           \
  STAGE_CODE;                                                                  \
  GG_BAR();                                                                    \
  GG_LG0();                                                                    \
  GG_MFMA(S0);                                                                 \
  GG_READ_A(BUF, (S0) + 1);                                                    \
  GG_LG0();                                                                    \
  GG_MFMA((S0) + 1);                                                           \
  if (DO_VM) { GG_VM4(); }                                                     \
  GG_BAR();

__global__ __launch_bounds__(512, 2) void gemm_geglu8(const bf16* __restrict__ A,
    const bf16* __restrict__ Wt, const float* __restrict__ gb,
    bf16* __restrict__ Cv, int K)
{
  __shared__ alignas(16) bf16 As[2][256 * 64];
  __shared__ alignas(16) bf16 Bs[2][256 * 64];
  const int tid = threadIdx.x;
  // persistent mapping: 256 blocks; XCD k (= b%8) gets m-panels 8k..8k+7
  // (2 MB of A, L2-resident); each block sweeps 4 consecutive n-tiles.
  const int logical = (blockIdx.x & 7) * 32 + (blockIdx.x >> 3);
  const int m0 = (logical >> 2) * 256;
  const int ng = logical & 3;            // n-group: tiles 4*ng .. 4*ng+3
  const int lane = tid & 63;
  const int wave = tid >> 6;             // 0..7
  const int wm = wave >> 2;              // 0..1 -> 128-row half of M-tile
  const int wn = (wave & 3) * 64;        // 4 strips of 64 interleaved cols
  const int fr = lane & 15;
  const int fq = lane >> 4;
  const int sr8 = lane >> 3;                    // row within 8-row staging group
  const int sgl = ((lane & 7) ^ sr8) * 8;       // swizzled source granule (elems)

  // staging: wave w covers rows half*128 + w*16 + {sr8, sr8+8}
  const bf16* gaB = A + (size_t)(m0 + wave * 16 + sr8) * K + sgl;

  auto stageA = [&](int buf, int half, int kt) {
    const bf16* g = gaB + (size_t)(half * 128) * K + kt;
    bf16* l = &As[buf][(half * 128 + wave * 16) * 64];
    gl_lds16(g, l);  gl_lds16(g + (size_t)8 * K, l + 8 * 64);
  };
  auto stageB = [&](int buf, int half, const bf16* bp, int kt) {
    const bf16* g = bp + (size_t)(half * 128) * K + kt;
    bf16* l = &Bs[buf][(half * 128 + wave * 16) * 64];
    gl_lds16(g, l);  gl_lds16(g + (size_t)8 * K, l + 8 * 64);
  };

  f32x4 acc[8][4];
  short8 af[2][2];
  short8 bfv[4][2];

  // per-thread B base for n-tile 4*ng; n-tile stride = 256 rows * K elems
  const bf16* bcur = Wt + (size_t)(ng * 4 * 256 + wave * 16 + sr8) * K + sgl;
  const size_t bstep = (size_t)256 * K;

  // prologue (once per kernel): tile0 A+B, tile1(K-step 64) B; drain to 4
  stageA(0, 0, 0); stageA(0, 1, 0); stageB(0, 0, bcur, 0); stageB(0, 1, bcur, 0);
  stageB(1, 0, bcur, 64); stageB(1, 1, bcur, 64);
  GG_VM4();
  GG_BAR();

  #pragma unroll 1
  for (int nt = 0; nt < 4; nt++) {
    const bf16* bnext = (nt < 3) ? (bcur + bstep) : bcur;   // last: dummy re-stage
    #pragma unroll
    for (int i = 0; i < 8; i++)
      #pragma unroll
      for (int j = 0; j < 4; j++) acc[i][j] = (f32x4){0.f, 0.f, 0.f, 0.f};

    // generic iterations t0 = 0,128,256 (all staged K within this tile)
    #pragma unroll 1
    for (int t0 = 0; t0 < 384; t0 += 128) {
      const int kA1 = t0 + 64, kN2 = t0 + 128, kN3 = t0 + 192;
      // alpha: K-step t0 (buf0) strips 0-1; stage A(t0+64) -> As[1]
      GG_PHASE(0, 0, { stageA(1, 0, kA1); stageA(1, 1, kA1); }, false)
      // beta: strips 2-3; stage B(t0+128) -> Bs[0]; VM4 drains A/B(t0+64)
      GG_PHASE(0, 2, { stageB(0, 0, bcur, kN2); stageB(0, 1, bcur, kN2); }, true)
      // gamma: K-step t0+64 (buf1) strips 0-1; stage A(t0+128) -> As[0]
      GG_PHASE(1, 0, { stageA(0, 0, kN2); stageA(0, 1, kN2); }, false)
      // delta: strips 2-3; stage B(t0+192) -> Bs[1]; VM4 drains A/B(t0+128)
      GG_PHASE(1, 2, { stageB(1, 0, bcur, kN3); stageB(1, 1, bcur, kN3); }, true)
    }
    // final iteration t0=384: cross-tile prefetch (A wraps to kt=0, B -> bnext)
    GG_PHASE(0, 0, { stageA(1, 0, 448); stageA(1, 1, 448); }, false)
    GG_PHASE(0, 2, { stageB(0, 0, bnext, 0); stageB(0, 1, bnext, 0); }, true)
    GG_PHASE(1, 0, { stageA(0, 0, 0); stageA(0, 1, 0); }, false)
    GG_PHASE(1, 2, { stageB(1, 0, bnext, 64); stageB(1, 1, bnext, 64); }, true)

    // epilogue for this n-tile (overlaps next tile's in-flight staging):
    // n-frags pair up as (a, gate) per 16-col granule
    const int cbase = ((ng * 4 + nt) * 256 + wn) >> 1;
    #pragma unroll
    for (int pi = 0; pi < 2; pi++) {
      int col = cbase + pi * 16 + fr;
      float ba = gb[col];
      float bg = gb[2048 + col];
      #pragma unroll
      for (int mi = 0; mi < 8; mi++) {
        int mbase = m0 + wm * 128 + mi * 16 + fq * 4;
        #pragma unroll
        for (int r = 0; r < 4; r++) {
          float a = acc[mi][2 * pi][r] + ba;
          float g = acc[mi][2 * pi + 1][r] + bg;
          Cv[(size_t)(mbase + r) * 2048 + col] = f2b(a * fast_gelu(g));
        }
      }
    }
    bcur = bnext;
  }
}

// ---------------- MSDA: degenerate deformable attention (Hl=L, Wl=1) ------
// sa: [M][256] fp32: cols 0..127 = sampling offsets, 128..191 = attn logits
__global__ __launch_bounds__(256) void msda_k(const float* __restrict__ sa,
    const bf16* __restrict__ v2, bf16* __restrict__ outp)
{
  int unit = blockIdx.x * 4 + (threadIdx.x >> 6);  // (b*L+l)*8 + h
  int lane = threadIdx.x & 63;
  int m = unit >> 3;
  int h = unit & 7;
  int b = m >> 12;                                  // L = 4096
  const float* lg = &sa[(size_t)m * 256 + 128 + h * 8];
  float w[8], mx = -1e30f;
  #pragma unroll
  for (int p = 0; p < 8; p++) { w[p] = lg[p]; mx = fmaxf(mx, w[p]); }
  float sum = 0.f;
  #pragma unroll
  for (int p = 0; p < 8; p++) { w[p] = expf(w[p] - mx); sum += w[p]; }
  float rs = 1.f / sum;
  const float* op = &sa[(size_t)m * 256 + h * 16];
  size_t vbase = ((size_t)b * 4096) * 512 + h * 64 + lane;
  float acc = 0.f;
  #pragma unroll
  for (int p = 0; p < 8; p++) {
    float ox = op[p * 2 + 0], oy = op[p * 2 + 1];
    float gx = 2.f * (0.5f + ox) - 1.f;
    float px = ((gx + 1.f) * 1.f - 1.f) * 0.5f;              // = ox (mirrors ref fp ops)
    float gy = 2.f * (0.5f + oy * (1.f / 4096.f)) - 1.f;
    float py = ((gy + 1.f) * 4096.f - 1.f) * 0.5f;           // = oy + 2047.5
    float x0 = floorf(px), y0 = floorf(py);
    float lx = px - x0, ly = py - y0;
    int xi = (int)x0;
    int yi = (int)y0;
    float wx = (xi == 0) ? (1.f - lx) : ((xi == -1) ? lx : 0.f);
    if (wx != 0.f) {                         // wave-uniform branch
      float s = 0.f;
      if (yi >= 0 && yi < 4096)  s += (1.f - ly) * b2f(v2[vbase + (size_t)yi * 512]);
      if (yi >= -1 && yi < 4095) s += ly * b2f(v2[vbase + (size_t)(yi + 1) * 512]);
      acc += w[p] * rs * wx * s;
    }
  }
  outp[(size_t)m * 512 + h * 64 + lane] = f2b(acc);
}

// =========================================================================
extern "C" void kernel_launch(void* const* d_in, const int* in_sizes, int n_in,
                              void* d_out, int out_size, void* d_ws, size_t ws_size,
                              hipStream_t stream)
{
  if (n_in < 27) return;
  const float* x       = (const float*)d_in[0];
  const float* gn_g    = (const float*)d_in[1];
  const float* gn_b    = (const float*)d_in[2];
  const float* pin_w   = (const float*)d_in[3];
  const float* pin_b   = (const float*)d_in[4];
  const float* ln1_g   = (const float*)d_in[5];
  const float* ln1_b   = (const float*)d_in[6];
  const float* vproj_w = (const float*)d_in[7];
  const float* vproj_b = (const float*)d_in[8];
  const float* mvp_w   = (const float*)d_in[9];
  const float* mvp_b   = (const float*)d_in[10];
  const float* soff_w  = (const float*)d_in[11];
  const float* soff_b  = (const float*)d_in[12];
  const float* attw_w  = (const float*)d_in[13];
  const float* attw_b  = (const float*)d_in[14];
  const float* mop_w   = (const float*)d_in[15];
  const float* mop_b   = (const float*)d_in[16];
  const float* dout_w  = (const float*)d_in[17];
  const float* dout_b  = (const float*)d_in[18];
  const float* ln3_g   = (const float*)d_in[19];
  const float* ln3_b   = (const float*)d_in[20];
  const float* geglu_w = (const float*)d_in[21];
  const float* geglu_b = (const float*)d_in[22];
  const float* dense_w = (const float*)d_in[23];
  const float* dense_b = (const float*)d_in[24];
  const float* pout_w  = (const float*)d_in[25];
  const float* pout_b  = (const float*)d_in[26];
  float* out = (float*)d_out;

  char* ws = (char*)d_ws;
  size_t off = 0;
  auto alloc = [&](size_t bytes) -> char* {
    off = (off + 255) & ~(size_t)255;
    char* p = ws + off;
    off += bytes;
    return p;
  };
  // persistent weights (bf16, transposed)
  bf16* wtPin   = (bf16*)alloc(512 * 512 * 2);
  bf16* wtBig   = (bf16*)alloc(768 * 512 * 2);     // [vproj 512 | soff 128 | attw 64 | pad 64]
  bf16* wtMvp   = (bf16*)alloc(512 * 512 * 2);
  bf16* wtMop   = (bf16*)alloc(512 * 512 * 2);
  bf16* wtDout  = (bf16*)alloc(512 * 512 * 2);
  bf16* wtPout  = (bf16*)alloc(512 * 512 * 2);
  bf16* wtGeglu = (bf16*)alloc((size_t)4096 * 512 * 2);   // granule-16 interleaved
  bf16* wtDense = (bf16*)alloc((size_t)512 * 2048 * 2);
  float* biasBig = (float*)alloc(768 * 4);
  float* stats   = (float*)alloc(64 * 4);
  // activation regions with liveness-checked unions
  char* A  = alloc(32 * MB);  // t32 (early) | hn@0 (16MB) + t3@16MB
  char* Cg = alloc(32 * MB);  // t2 (fp32)
  char* D  = alloc(64 * MB);  // xnt@0, v@16, v2@32, msda@48
  char* E  = alloc(64 * MB);  // q16@0, sa32@16 (16MB), m2@32 (16MB) | ffin@0 (64MB)
  if (off > ws_size) return;  // workspace too small — fail loudly (zero output)

  float* t32   = (float*)A;
  bf16*  hn    = (bf16*)A;
  bf16*  t3    = (bf16*)(A + 16 * MB);
  float* t2    = (float*)Cg;
  bf16*  xnt   = (bf16*)D;
  bf16*  v16   = (bf16*)(D + 16 * MB);
  bf16*  v2b   = (bf16*)(D + 32 * MB);
  bf16*  msda  = (bf16*)(D + 48 * MB);
  bf16*  q16   = (bf16*)E;
  float* sa32  = (float*)(E + 16 * MB);
  bf16*  m2    = (bf16*)(E + 32 * MB);
  bf16*  ffin  = (bf16*)E;

  hipMemsetAsync(stats, 0, 64 * 4, stream);
  pack_bias_big<<<3, 256, 0, stream>>>(vproj_b, soff_b, attw_b, biasBig);

  // fused transpose: 11 jobs
  TransJobs J{};
  auto setJob = [&](int j, const float* src, bf16* dst, int K, int N, int Npad,
                    int ss, int sc, int a, int b) {
    J.src[j] = src; J.dst[j] = dst; J.K[j] = K; J.N[j] = N;
    J.srcStride[j] = ss; J.srcColOff[j] = sc; J.a[j] = a; J.b[j] = b;
    J.tileStart[j + 1] = J.tileStart[j] + (K / 32) * (Npad / 32);
  };
  J.tileStart[0] = 0;
  setJob(0,  pin_w,   wtPin,   512, 512,  512,  512,  0,    1, 0);
  setJob(1,  vproj_w, wtBig,   512, 512,  512,  512,  0,    1, 0);
  setJob(2,  soff_w,  wtBig,   512, 128,  128,  128,  0,    1, 512);
  setJob(3,  attw_w,  wtBig,   512, 64,   128,  64,   0,    1, 640);
  setJob(4,  mvp_w,   wtMvp,   512, 512,  512,  512,  0,    1, 0);
  setJob(5,  mop_w,   wtMop,   512, 512,  512,  512,  0,    1, 0);
  setJob(6,  dout_w,  wtDout,  512, 512,  512,  512,  0,    1, 0);
  setJob(7,  pout_w,  wtPout,  512, 512,  512,  512,  0,    1, 0);
  setJob(8,  geglu_w, wtGeglu, 512, 2048, 2048, 4096, 0,    2, 0);  // a-half
  setJob(9,  geglu_w, wtGeglu, 512, 2048, 2048, 4096, 2048, 2, 1);  // gate-half
  setJob(10, dense_w, wtDense, 2048, 512, 512,  512,  0,    1, 0);
  transpose_all<<<J.tileStart[11], dim3(32, 8), 0, stream>>>(J);

  dim3 tb(32, 8);
  gn_partial<<<512, 256, 0, stream>>>(x, stats);
  gn_apply_t<<<dim3(128, 16, 4), tb, 0, stream>>>(x, stats, gn_g, gn_b, xnt);

  // t = xnt @ pin + b   (fp32 trunk)
  gemm_bt<float, float, 0><<<dim3(4, 128), 512, 0, stream>>>(
      xnt, wtPin, pin_b, nullptr, t32, nullptr, M_, 512, 512);
  // q = LN1(t)
  layernorm_k<<<4096, 256, 0, stream>>>(t32, ln1_g, ln1_b, q16);
  // fused: value = q @ vproj (bf16) ; sa = q @ [soff|attw] (fp32)
  gemm_bt<bf16, float, 4><<<dim3(6, 128), 512, 0, stream>>>(
      q16, wtBig, biasBig, nullptr, v16, sa32, M_, 768, 512);
  // v2 = value @ mvp
  gemm_bt<bf16, float, 0><<<dim3(4, 128), 512, 0, stream>>>(
      v16, wtMvp, mvp_b, nullptr, v2b, nullptr, M_, 512, 512);
  msda_k<<<32768, 256, 0, stream>>>(sa32, v2b, msda);
  // m2 = msda @ mop + b + q ; t2 = m2 @ dout + b + t (fp32 trunk)
  gemm_bt<bf16, bf16, 1><<<dim3(4, 128), 512, 0, stream>>>(
      msda, wtMop, mop_b, q16, m2, nullptr, M_, 512, 512);
  gemm_bt<float, float, 1><<<dim3(4, 128), 512, 0, stream>>>(
      m2, wtDout, dout_b, t32, t2, nullptr, M_, 512, 512);
  // hn = LN3(t2)
  layernorm_k<<<4096, 256, 0, stream>>>(t2, ln3_g, ln3_b, hn);
  // ffin = (hn @ Wa + ba) * gelu(hn @ Wg + bg) — persistent 256^2 GEGLU
  gemm_geglu8<<<256, 512, 0, stream>>>(hn, wtGeglu, geglu_b, ffin, 512);
  // t3 = ffin @ dense + b + t2
  gemm_bt<bf16, float, 1><<<dim3(4, 128), 512, 0, stream>>>(
      ffin, wtDense, dense_b, t2, t3, nullptr, M_, 512, 2048);
  // out[b,c,l] = (t3 @ pout + b)[b,l,c] + x[b,c,l]   (fused transpose epilogue)
  gemm_bt<float, float, 3><<<dim3(4, 128), 512, 0, stream>>>(
      t3, wtPout, pout_b, x, out, nullptr, M_, 512, 512);
}

// Round 4
// 509.650 us; speedup vs baseline: 1.1004x; 1.1004x over previous
//
#include <hip/hip_runtime.h>
#include <hip/hip_bf16.h>
#include <math.h>

using bf16 = __hip_bfloat16;
typedef __attribute__((ext_vector_type(8))) short short8;
typedef __attribute__((ext_vector_type(4))) float f32x4;

static constexpr int B_ = 4, C_ = 512, L_ = 4096, M_ = 16384;
static constexpr size_t MB = 1ull << 20;

__device__ __forceinline__ float b2f(bf16 v){ return __bfloat162float(v); }
__device__ __forceinline__ bf16  f2b(float v){ return __float2bfloat16(v); }

// async global -> LDS, 16B per lane, lane l lands at (wave-uniform base) + l*16
__device__ __forceinline__ void gl_lds16(const bf16* g, bf16* l) {
  __builtin_amdgcn_global_load_lds(
      (const __attribute__((address_space(1))) unsigned int*)g,
      (__attribute__((address_space(3))) unsigned int*)l, 16, 0, 0);
}

// gelu(g) = 0.5 g (1 + erf(g/sqrt2)); erf via A&S 7.1.26 (|eps| < 1.5e-7)
__device__ __forceinline__ float fast_gelu(float g) {
  float t  = g * 0.70710678118654752f;
  float at = fabsf(t);
  float k  = 1.f / (1.f + 0.3275911f * at);
  float poly = k * (0.254829592f + k * (-0.284496736f + k * (1.421413741f +
               k * (-1.453152027f + k * 1.061405429f))));
  float erfv = 1.f - poly * __expf(-at * at);
  erfv = __builtin_copysignf(erfv, t);
  return 0.5f * g * (1.f + erfv);
}

// ---------------- fused weight transpose: 11 jobs in one dispatch ----------
// mode a==1: dst row = n + b.  mode a==2: granule-16 geglu interleave:
//   dst row = ((n>>4)<<5) + b*16 + (n&15)   (b=0: a-half, b=1: gate-half)
struct TransJobs {
  const float* src[11];
  bf16* dst[11];
  int K[11], N[11], srcStride[11], srcColOff[11], a[11], b[11];
  int tileStart[12];
};

__global__ __launch_bounds__(256) void transpose_all(TransJobs J)
{
  __shared__ float tile[32][33];
  int t = blockIdx.x;
  int j = 0;
  #pragma unroll
  for (int q = 0; q < 10; q++) if (t >= J.tileStart[q + 1]) j = q + 1;
  t -= J.tileStart[j];
  const int kTiles = J.K[j] >> 5;
  const int k0 = (t % kTiles) * 32, n0 = (t / kTiles) * 32;
  const int tx = threadIdx.x, ty = threadIdx.y;
  const float* src = J.src[j];
  const int N = J.N[j], ss = J.srcStride[j], sc = J.srcColOff[j];
  #pragma unroll
  for (int i = 0; i < 32; i += 8) {
    int k = k0 + ty + i, n = n0 + tx;
    tile[ty + i][tx] = (n < N) ? src[(size_t)k * ss + sc + n] : 0.f;
  }
  __syncthreads();
  bf16* dst = J.dst[j];
  const int a = J.a[j], b = J.b[j], K = J.K[j];
  #pragma unroll
  for (int i = 0; i < 32; i += 8) {
    int n = n0 + ty + i, k = k0 + tx;
    int row = (a == 2) ? (((n >> 4) << 5) + b * 16 + (n & 15)) : (n + b);
    dst[(size_t)row * K + k] = f2b(tile[tx][ty + i]);
  }
}

// combined bias [vproj(512) | soff(128) | attw(64) | zero(64)]
__global__ void pack_bias_big(const float* __restrict__ vb,
    const float* __restrict__ sb, const float* __restrict__ ab,
    float* __restrict__ bp){
  int i = blockIdx.x * 256 + threadIdx.x;   // 768 threads
  float v = 0.f;
  if (i < 512) v = vb[i];
  else if (i < 640) v = sb[i - 512];
  else if (i < 704) v = ab[i - 640];
  bp[i] = v;
}

// ---------------- GroupNorm stats (sum, sumsq per (b,g)) ----------------
__global__ __launch_bounds__(256) void gn_partial(const float* __restrict__ x,
                                                  float* __restrict__ stats)
{
  int bg = blockIdx.x >> 4;
  int sc = blockIdx.x & 15;
  size_t base = (size_t)bg * 262144 + (size_t)sc * 16384;
  int tid = threadIdx.x;
  float s = 0.f, s2 = 0.f;
  #pragma unroll
  for (int i = 0; i < 8; i++) {
    size_t o = base + ((size_t)i * 256 + tid) * 8;
    float4 a = *reinterpret_cast<const float4*>(&x[o]);
    float4 b = *reinterpret_cast<const float4*>(&x[o + 4]);
    s  += a.x + a.y + a.z + a.w + b.x + b.y + b.z + b.w;
    s2 += a.x*a.x + a.y*a.y + a.z*a.z + a.w*a.w
        + b.x*b.x + b.y*b.y + b.z*b.z + b.w*b.w;
  }
  #pragma unroll
  for (int o = 32; o; o >>= 1) { s += __shfl_xor(s, o, 64); s2 += __shfl_xor(s2, o, 64); }
  __shared__ float ls[4], ls2[4];
  int wave = tid >> 6, lane = tid & 63;
  if (lane == 0) { ls[wave] = s; ls2[wave] = s2; }
  __syncthreads();
  if (tid == 0) {
    atomicAdd(&stats[bg * 2 + 0], ls[0] + ls[1] + ls[2] + ls[3]);
    atomicAdd(&stats[bg * 2 + 1], ls2[0] + ls2[1] + ls2[2] + ls2[3]);
  }
}

// ---------------- GN apply + transpose (B,C,L) -> (B*L, C) bf16 ----------
__global__ __launch_bounds__(256) void gn_apply_t(const float* __restrict__ x,
    const float* __restrict__ stats, const float* __restrict__ gg,
    const float* __restrict__ gb, bf16* __restrict__ xnt)
{
  __shared__ float tile[32][33];
  int b = blockIdx.z, c0 = blockIdx.y * 32, l0 = blockIdx.x * 32;
  int tx = threadIdx.x, ty = threadIdx.y;
  #pragma unroll
  for (int i = 0; i < 32; i += 8) {
    int c = c0 + ty + i, l = l0 + tx;
    int grp = b * 8 + (c >> 6);
    float sum = stats[grp * 2], ss = stats[grp * 2 + 1];
    float mu = sum * (1.f / 262144.f);
    float inv = rsqrtf(ss * (1.f / 262144.f) - mu * mu + 1e-5f);
    float v = x[((size_t)b * 512 + c) * 4096 + l];
    tile[ty + i][tx] = (v - mu) * inv * gg[c] + gb[c];
  }
  __syncthreads();
  #pragma unroll
  for (int i = 0; i < 32; i += 8) {
    int l = l0 + ty + i, c = c0 + tx;
    xnt[((size_t)b * 4096 + l) * 512 + c] = f2b(tile[tx][ty + i]);
  }
}

// ---------------- LayerNorm over C=512: fp32 in, bf16 out, 1 wave/row -----
__global__ __launch_bounds__(256) void layernorm_k(const float* __restrict__ X,
    const float* __restrict__ g, const float* __restrict__ b, bf16* __restrict__ Y)
{
  int row = blockIdx.x * 4 + (threadIdx.x >> 6);
  int lane = threadIdx.x & 63;
  const float* xr = X + (size_t)row * 512 + lane * 8;
  float4 a = *reinterpret_cast<const float4*>(xr);
  float4 c = *reinterpret_cast<const float4*>(xr + 4);
  float v[8] = {a.x, a.y, a.z, a.w, c.x, c.y, c.z, c.w};
  float s = 0.f, s2 = 0.f;
  #pragma unroll
  for (int i = 0; i < 8; i++) { s += v[i]; s2 += v[i] * v[i]; }
  #pragma unroll
  for (int o = 32; o; o >>= 1) { s += __shfl_xor(s, o, 64); s2 += __shfl_xor(s2, o, 64); }
  float mu = s * (1.f / 512.f);
  float inv = rsqrtf(s2 * (1.f / 512.f) - mu * mu + 1e-5f);
  float4 g0 = *reinterpret_cast<const float4*>(&g[lane * 8]);
  float4 g1 = *reinterpret_cast<const float4*>(&g[lane * 8 + 4]);
  float4 b0 = *reinterpret_cast<const float4*>(&b[lane * 8]);
  float4 b1 = *reinterpret_cast<const float4*>(&b[lane * 8 + 4]);
  float gv[8] = {g0.x, g0.y, g0.z, g0.w, g1.x, g1.y, g1.z, g1.w};
  float bv[8] = {b0.x, b0.y, b0.z, b0.w, b1.x, b1.y, b1.z, b1.w};
  bf16 outv[8];
  #pragma unroll
  for (int i = 0; i < 8; i++) outv[i] = f2b((v[i] - mu) * inv * gv[i] + bv[i]);
  *reinterpret_cast<uint4*>(Y + (size_t)row * 512 + lane * 8) =
      *reinterpret_cast<const uint4*>(outv);
}

// --- MFMA GEMM, 128x128 tile, 512 threads (8 waves, 2x4 frags/wave) -------
// BK=64 full-line staging + XOR swizzle, dbuf. LDS 64 KB -> 2 blocks/CU,
// 16 waves/CU = 4 waves/SIMD. Round-3: XCD-contiguous block swizzle —
// hw id round-robins XCDs on dispatch order, so remap hw -> logical with
// (hw&7)*(nwg/8)+hw>>3 (bijective, all grids %8==0): each XCD then owns
// contiguous logical blocks = whole m-panels with all their n-blocks
// (A-panel read once per XCD L2 instead of per-XCD-per-n-block).
// EPI: 0 none | 1 += res[idx] | 3 transpose+residual fp32 out
// EPI 4: n0<512 -> bf16 Cv[m*512+n]; n0>=512 -> fp32 out2[m*256+n-512]
template<typename TOUT, typename TRES, int EPI>
__global__ __launch_bounds__(512) void gemm_bt(const bf16* __restrict__ A,
    const bf16* __restrict__ Bt, const float* __restrict__ bias,
    const TRES* __restrict__ res, TOUT* __restrict__ Cv,
    float* __restrict__ out2, int M, int N, int K)
{
  __shared__ alignas(16) bf16 As[2][128 * 64];
  __shared__ alignas(16) bf16 Bs[2][128 * 64];
  const int tid = threadIdx.x;
  const int gx = gridDim.x;
  const int nwg = gx * gridDim.y;
  int hw = blockIdx.y * gx + blockIdx.x;
  int lg = (hw & 7) * (nwg >> 3) + (hw >> 3);    // nwg % 8 == 0 for all grids
  const int m0 = (lg / gx) * 128;
  const int n0 = (lg % gx) * 128;
  const int lane = tid & 63;
  const int wave = tid >> 6;            // 0..7
  const int wm = (wave & 3) * 32;       // 4 m-strips of 32 rows
  const int wn = (wave >> 2) * 64;      // 2 n-strips of 64 cols
  const int fr = lane & 15;
  const int fq = lane >> 4;
  const int sr8 = lane >> 3;                    // row within 8-row staging group
  const int sgl = ((lane & 7) ^ sr8) * 8;       // swizzled source granule (elems)

  const bf16* gaBase = A  + (size_t)(m0 + wave * 16 + sr8) * K + sgl;
  const bf16* gbBase = Bt + (size_t)(n0 + wave * 16 + sr8) * K + sgl;

  f32x4 acc[2][4];
  #pragma unroll
  for (int i = 0; i < 2; i++)
    #pragma unroll
    for (int j = 0; j < 4; j++) acc[i][j] = (f32x4){0.f, 0.f, 0.f, 0.f};

  auto stage = [&](int buf, int kt) {
    const bf16* ga = gaBase + kt;
    const bf16* gb = gbBase + kt;
    bf16* la = &As[buf][wave * 16 * 64];
    bf16* lb = &Bs[buf][wave * 16 * 64];
    gl_lds16(ga, la);                    gl_lds16(ga + (size_t)8 * K, la + 8 * 64);
    gl_lds16(gb, lb);                    gl_lds16(gb + (size_t)8 * K, lb + 8 * 64);
  };

  stage(0, 0);
  int cur = 0;
  for (int kt = 0; kt < K; kt += 64) {
    __syncthreads();                            // drains stage(cur)
    if (kt + 64 < K) stage(cur ^ 1, kt + 64);   // async prefetch next tile
    #pragma unroll
    for (int ko = 0; ko < 2; ko++) {
      const int pa = ((ko * 4 + fq) ^ (fr & 7)) * 8;
      short8 af[2], bfv[4];
      #pragma unroll
      for (int mi = 0; mi < 2; mi++)
        af[mi] = *reinterpret_cast<const short8*>(&As[cur][(wm + mi * 16 + fr) * 64 + pa]);
      #pragma unroll
      for (int ni = 0; ni < 4; ni++)
        bfv[ni] = *reinterpret_cast<const short8*>(&Bs[cur][(wn + ni * 16 + fr) * 64 + pa]);
      #pragma unroll
      for (int mi = 0; mi < 2; mi++)
        #pragma unroll
        for (int ni = 0; ni < 4; ni++)
          acc[mi][ni] = __builtin_amdgcn_mfma_f32_16x16x32_bf16(af[mi], bfv[ni],
                                                                acc[mi][ni], 0, 0, 0);
    }
    cur ^= 1;
  }

  // epilogue: C/D layout col = lane&15, row = (lane>>4)*4 + reg
  #pragma unroll
  for (int ni = 0; ni < 4; ni++) {
    int n = n0 + wn + ni * 16 + fr;
    float bv = bias[n];
    #pragma unroll
    for (int mi = 0; mi < 2; mi++) {
      int mbase = m0 + wm + mi * 16 + fq * 4;
      if (EPI == 3) {
        int b = mbase >> 12, l = mbase & 4095;
        size_t o = ((size_t)(b * 512 + n) << 12) + l;
        float4 xr = *reinterpret_cast<const float4*>(&((const float*)res)[o]);
        float4 vv;
        vv.x = acc[mi][ni][0] + bv + xr.x;
        vv.y = acc[mi][ni][1] + bv + xr.y;
        vv.z = acc[mi][ni][2] + bv + xr.z;
        vv.w = acc[mi][ni][3] + bv + xr.w;
        *reinterpret_cast<float4*>(&((float*)Cv)[o]) = vv;
      } else if (EPI == 4) {
        #pragma unroll
        for (int r = 0; r < 4; r++) {
          float v = acc[mi][ni][r] + bv;
          if (n0 < 512) ((bf16*)Cv)[(size_t)(mbase + r) * 512 + n] = f2b(v);
          else          out2[(size_t)(mbase + r) * 256 + (n - 512)] = v;
        }
      } else {
        #pragma unroll
        for (int r = 0; r < 4; r++) {
          size_t idx = (size_t)(mbase + r) * N + n;
          float v = acc[mi][ni][r] + bv;
          if (EPI == 1) {
            float rv;
            if constexpr (sizeof(TRES) == 2) rv = b2f(((const bf16*)res)[idx]);
            else                             rv = ((const float*)res)[idx];
            v += rv;
          }
          if constexpr (sizeof(TOUT) == 2) ((bf16*)Cv)[idx] = f2b(v);
          else                             ((float*)Cv)[idx] = v;
        }
      }
    }
  }
}

// ====================== GEGLU GEMM — 256x256, 4-phase/2-tile schedule =====
// (Round-2 verified version, reverted to after the persistent experiment
// regressed: A re-read x4 thrashed per-XCD L2 -> FETCH/WRITE amplification.)
// 2 barrier-pairs per K-tile; second strip's ds_reads issue under first
// cluster's MFMA shadow; sched_barrier(0) after every wait (rule #18);
// bijective XCD swizzle. vmcnt(4): at each VM4 the tiles consumed next
// phase are drained, newest 2 half-tiles float.
#define GG_BAR() __builtin_amdgcn_s_barrier()
#define GG_LG0() do { asm volatile("s_waitcnt lgkmcnt(0)" ::: "memory"); \
                      __builtin_amdgcn_sched_barrier(0); } while (0)
#define GG_VM4() do { asm volatile("s_waitcnt vmcnt(4)" ::: "memory"); \
                      __builtin_amdgcn_sched_barrier(0); } while (0)

#define GG_READ_A(BUF, S)                                                      \
  {                                                                            \
    _Pragma("unroll") for (int mi = 0; mi < 2; mi++)                           \
      _Pragma("unroll") for (int ko = 0; ko < 2; ko++) {                       \
        const int row = wm * 128 + ((S) * 2 + mi) * 16 + fr;                   \
        const int pa = ((ko * 4 + fq) ^ (fr & 7)) * 8;                         \
        af[mi][ko] = *reinterpret_cast<const short8*>(&As[BUF][row * 64 + pa]);\
      }                                                                        \
  }

#define GG_READ_B(BUF)                                                         \
  {                                                                            \
    _Pragma("unroll") for (int ni = 0; ni < 4; ni++)                           \
      _Pragma("unroll") for (int ko = 0; ko < 2; ko++) {                       \
        const int row = wn + ni * 16 + fr;                                     \
        const int pa = ((ko * 4 + fq) ^ (fr & 7)) * 8;                         \
        bfv[ni][ko] = *reinterpret_cast<const short8*>(&Bs[BUF][row * 64 + pa]); \
      }                                                                        \
  }

#define GG_MFMA(S)                                                             \
  __builtin_amdgcn_s_setprio(1);                                               \
  _Pragma("unroll") for (int mi = 0; mi < 2; mi++)                             \
    _Pragma("unroll") for (int ni = 0; ni < 4; ni++)                           \
      _Pragma("unroll") for (int ko = 0; ko < 2; ko++)                         \
        acc[(S) * 2 + mi][ni] = __builtin_amdgcn_mfma_f32_16x16x32_bf16(       \
            af[mi][ko], bfv[ni][ko], acc[(S) * 2 + mi][ni], 0, 0, 0);          \
  __builtin_amdgcn_s_setprio(0);

// one barrier-pair phase: strips S0,S0+1 of buf BUF; STAGE issued pre-bar
#define GG_PHASE(BUF, S0, STAGE_CODE, DO_VM)                                   \
  GG_READ_A(BUF, S0);                                                          \
  if ((S0) == 0) { GG_READ_B(BUF); }                                           \
  STAGE_CODE;                                                                  \
  GG_BAR();                                                                    \
  GG_LG0();                                                                    \
  GG_MFMA(S0);                                                                 \
  GG_READ_A(BUF, (S0) + 1);                                                    \
  GG_LG0();                                                                    \
  GG_MFMA((S0) + 1);                                                           \
  if (DO_VM) { GG_VM4(); }                                                     \
  GG_BAR();

__global__ __launch_bounds__(512, 2) void gemm_geglu8(const bf16* __restrict__ A,
    const bf16* __restrict__ Wt, const float* __restrict__ gb,
    bf16* __restrict__ Cv, int K)
{
  __shared__ alignas(16) bf16 As[2][256 * 64];
  __shared__ alignas(16) bf16 Bs[2][256 * 64];
  const int tid = threadIdx.x;
  // bijective XCD swizzle for grid (16,64): XCD k gets 8 contiguous m-panels
  int bid = blockIdx.y * 16 + blockIdx.x;        // 1024 blocks, 1024%8==0
  bid = (bid & 7) * 128 + (bid >> 3);
  const int m0 = (bid >> 4) * 256;
  const int n0 = (bid & 15) * 256;               // interleaved-row space
  const int lane = tid & 63;
  const int wave = tid >> 6;             // 0..7
  const int wm = wave >> 2;              // 0..1 -> 128-row half of M-tile
  const int wn = (wave & 3) * 64;        // 4 strips of 64 interleaved cols
  const int fr = lane & 15;
  const int fq = lane >> 4;
  const int sr8 = lane >> 3;                    // row within 8-row staging group
  const int sgl = ((lane & 7) ^ sr8) * 8;       // swizzled source granule (elems)

  // staging: wave w covers rows half*128 + w*16 + {sr8, sr8+8}
  const bf16* gaB = A  + (size_t)(m0 + wave * 16 + sr8) * K + sgl;
  const bf16* gbB = Wt + (size_t)(n0 + wave * 16 + sr8) * K + sgl;

  auto stageA = [&](int buf, int half, int kt) {
    const bf16* g = gaB + (size_t)(half * 128) * K + kt;
    bf16* l = &As[buf][(half * 128 + wave * 16) * 64];
    gl_lds16(g, l);  gl_lds16(g + (size_t)8 * K, l + 8 * 64);
  };
  auto stageB = [&](int buf, int half, int kt) {
    const bf16* g = gbB + (size_t)(half * 128) * K + kt;
    bf16* l = &Bs[buf][(half * 128 + wave * 16) * 64];
    gl_lds16(g, l);  gl_lds16(g + (size_t)8 * K, l + 8 * 64);
  };

  f32x4 acc[8][4];
  #pragma unroll
  for (int i = 0; i < 8; i++)
    #pragma unroll
    for (int j = 0; j < 4; j++) acc[i][j] = (f32x4){0.f, 0.f, 0.f, 0.f};

  // prologue: tile0 A+B, tile1 B (12 loads); wait oldest 8 (tile0 complete)
  stageA(0, 0, 0); stageA(0, 1, 0); stageB(0, 0, 0); stageB(0, 1, 0);
  stageB(1, 0, 64); stageB(1, 1, 64);
  GG_VM4();
  GG_BAR();

  short8 af[2][2];
  short8 bfv[4][2];
  for (int t0 = 0; t0 < K; t0 += 128) {
    const int kA1 = t0 + 64;                       // always < K (K%128==0)
    int kN2 = t0 + 128; if (kN2 >= K) kN2 = 0;     // dummy re-stage on tail
    int kN3 = t0 + 192; if (kN3 >= K) kN3 = 0;
    // alpha: tile T (buf0) strips 0-1; stage A(T+1) -> As[1]
    GG_PHASE(0, 0, { stageA(1, 0, kA1); stageA(1, 1, kA1); }, false)
    // beta: tile T strips 2-3; stage B(T+2) -> Bs[0]; VM4 drains A/B(T+1)
    GG_PHASE(0, 2, { stageB(0, 0, kN2); stageB(0, 1, kN2); }, true)
    // gamma: tile T+1 (buf1) strips 0-1; stage A(T+2) -> As[0]
    GG_PHASE(1, 0, { stageA(0, 0, kN2); stageA(0, 1, kN2); }, false)
    // delta: tile T+1 strips 2-3; stage B(T+3) -> Bs[1]; VM4 drains A/B(T+2)
    GG_PHASE(1, 2, { stageB(1, 0, kN3); stageB(1, 1, kN3); }, true)
  }

  // epilogue: n-frags pair up as (a, gate) per 16-col granule
  const int cbase = (n0 + wn) >> 1;
  #pragma unroll
  for (int pi = 0; pi < 2; pi++) {
    int col = cbase + pi * 16 + fr;
    float ba = gb[col];
    float bg = gb[2048 + col];
    #pragma unroll
    for (int mi = 0; mi < 8; mi++) {
      int mbase = m0 + wm * 128 + mi * 16 + fq * 4;
      #pragma unroll
      for (int r = 0; r < 4; r++) {
        float a = acc[mi][2 * pi][r] + ba;
        float g = acc[mi][2 * pi + 1][r] + bg;
        Cv[(size_t)(mbase + r) * 2048 + col] = f2b(a * fast_gelu(g));
      }
    }
  }
}

// ---------------- MSDA: degenerate deformable attention (Hl=L, Wl=1) ------
// sa: [M][256] fp32: cols 0..127 = sampling offsets, 128..191 = attn logits
__global__ __launch_bounds__(256) void msda_k(const float* __restrict__ sa,
    const bf16* __restrict__ v2, bf16* __restrict__ outp)
{
  int unit = blockIdx.x * 4 + (threadIdx.x >> 6);  // (b*L+l)*8 + h
  int lane = threadIdx.x & 63;
  int m = unit >> 3;
  int h = unit & 7;
  int b = m >> 12;                                  // L = 4096
  const float* lg = &sa[(size_t)m * 256 + 128 + h * 8];
  float w[8], mx = -1e30f;
  #pragma unroll
  for (int p = 0; p < 8; p++) { w[p] = lg[p]; mx = fmaxf(mx, w[p]); }
  float sum = 0.f;
  #pragma unroll
  for (int p = 0; p < 8; p++) { w[p] = expf(w[p] - mx); sum += w[p]; }
  float rs = 1.f / sum;
  const float* op = &sa[(size_t)m * 256 + h * 16];
  size_t vbase = ((size_t)b * 4096) * 512 + h * 64 + lane;
  float acc = 0.f;
  #pragma unroll
  for (int p = 0; p < 8; p++) {
    float ox = op[p * 2 + 0], oy = op[p * 2 + 1];
    float gx = 2.f * (0.5f + ox) - 1.f;
    float px = ((gx + 1.f) * 1.f - 1.f) * 0.5f;              // = ox (mirrors ref fp ops)
    float gy = 2.f * (0.5f + oy * (1.f / 4096.f)) - 1.f;
    float py = ((gy + 1.f) * 4096.f - 1.f) * 0.5f;           // = oy + 2047.5
    float x0 = floorf(px), y0 = floorf(py);
    float lx = px - x0, ly = py - y0;
    int xi = (int)x0;
    int yi = (int)y0;
    float wx = (xi == 0) ? (1.f - lx) : ((xi == -1) ? lx : 0.f);
    if (wx != 0.f) {                         // wave-uniform branch
      float s = 0.f;
      if (yi >= 0 && yi < 4096)  s += (1.f - ly) * b2f(v2[vbase + (size_t)yi * 512]);
      if (yi >= -1 && yi < 4095) s += ly * b2f(v2[vbase + (size_t)(yi + 1) * 512]);
      acc += w[p] * rs * wx * s;
    }
  }
  outp[(size_t)m * 512 + h * 64 + lane] = f2b(acc);
}

// =========================================================================
extern "C" void kernel_launch(void* const* d_in, const int* in_sizes, int n_in,
                              void* d_out, int out_size, void* d_ws, size_t ws_size,
                              hipStream_t stream)
{
  if (n_in < 27) return;
  const float* x       = (const float*)d_in[0];
  const float* gn_g    = (const float*)d_in[1];
  const float* gn_b    = (const float*)d_in[2];
  const float* pin_w   = (const float*)d_in[3];
  const float* pin_b   = (const float*)d_in[4];
  const float* ln1_g   = (const float*)d_in[5];
  const float* ln1_b   = (const float*)d_in[6];
  const float* vproj_w = (const float*)d_in[7];
  const float* vproj_b = (const float*)d_in[8];
  const float* mvp_w   = (const float*)d_in[9];
  const float* mvp_b   = (const float*)d_in[10];
  const float* soff_w  = (const float*)d_in[11];
  const float* soff_b  = (const float*)d_in[12];
  const float* attw_w  = (const float*)d_in[13];
  const float* attw_b  = (const float*)d_in[14];
  const float* mop_w   = (const float*)d_in[15];
  const float* mop_b   = (const float*)d_in[16];
  const float* dout_w  = (const float*)d_in[17];
  const float* dout_b  = (const float*)d_in[18];
  const float* ln3_g   = (const float*)d_in[19];
  const float* ln3_b   = (const float*)d_in[20];
  const float* geglu_w = (const float*)d_in[21];
  const float* geglu_b = (const float*)d_in[22];
  const float* dense_w = (const float*)d_in[23];
  const float* dense_b = (const float*)d_in[24];
  const float* pout_w  = (const float*)d_in[25];
  const float* pout_b  = (const float*)d_in[26];
  float* out = (float*)d_out;

  char* ws = (char*)d_ws;
  size_t off = 0;
  auto alloc = [&](size_t bytes) -> char* {
    off = (off + 255) & ~(size_t)255;
    char* p = ws + off;
    off += bytes;
    return p;
  };
  // persistent weights (bf16, transposed)
  bf16* wtPin   = (bf16*)alloc(512 * 512 * 2);
  bf16* wtBig   = (bf16*)alloc(768 * 512 * 2);     // [vproj 512 | soff 128 | attw 64 | pad 64]
  bf16* wtMvp   = (bf16*)alloc(512 * 512 * 2);
  bf16* wtMop   = (bf16*)alloc(512 * 512 * 2);
  bf16* wtDout  = (bf16*)alloc(512 * 512 * 2);
  bf16* wtPout  = (bf16*)alloc(512 * 512 * 2);
  bf16* wtGeglu = (bf16*)alloc((size_t)4096 * 512 * 2);   // granule-16 interleaved
  bf16* wtDense = (bf16*)alloc((size_t)512 * 2048 * 2);
  float* biasBig = (float*)alloc(768 * 4);
  float* stats   = (float*)alloc(64 * 4);
  // activation regions with liveness-checked unions
  char* A  = alloc(32 * MB);  // t32 (early) | hn@0 (16MB) + t3@16MB
  char* Cg = alloc(32 * MB);  // t2 (fp32)
  char* D  = alloc(64 * MB);  // xnt@0, v@16, v2@32, msda@48
  char* E  = alloc(64 * MB);  // q16@0, sa32@16 (16MB), m2@32 (16MB) | ffin@0 (64MB)
  if (off > ws_size) return;  // workspace too small — fail loudly (zero output)

  float* t32   = (float*)A;
  bf16*  hn    = (bf16*)A;
  bf16*  t3    = (bf16*)(A + 16 * MB);
  float* t2    = (float*)Cg;
  bf16*  xnt   = (bf16*)D;
  bf16*  v16   = (bf16*)(D + 16 * MB);
  bf16*  v2b   = (bf16*)(D + 32 * MB);
  bf16*  msda  = (bf16*)(D + 48 * MB);
  bf16*  q16   = (bf16*)E;
  float* sa32  = (float*)(E + 16 * MB);
  bf16*  m2    = (bf16*)(E + 32 * MB);
  bf16*  ffin  = (bf16*)E;

  hipMemsetAsync(stats, 0, 64 * 4, stream);
  pack_bias_big<<<3, 256, 0, stream>>>(vproj_b, soff_b, attw_b, biasBig);

  // fused transpose: 11 jobs
  TransJobs J{};
  auto setJob = [&](int j, const float* src, bf16* dst, int K, int N, int Npad,
                    int ss, int sc, int a, int b) {
    J.src[j] = src; J.dst[j] = dst; J.K[j] = K; J.N[j] = N;
    J.srcStride[j] = ss; J.srcColOff[j] = sc; J.a[j] = a; J.b[j] = b;
    J.tileStart[j + 1] = J.tileStart[j] + (K / 32) * (Npad / 32);
  };
  J.tileStart[0] = 0;
  setJob(0,  pin_w,   wtPin,   512, 512,  512,  512,  0,    1, 0);
  setJob(1,  vproj_w, wtBig,   512, 512,  512,  512,  0,    1, 0);
  setJob(2,  soff_w,  wtBig,   512, 128,  128,  128,  0,    1, 512);
  setJob(3,  attw_w,  wtBig,   512, 64,   128,  64,   0,    1, 640);
  setJob(4,  mvp_w,   wtMvp,   512, 512,  512,  512,  0,    1, 0);
  setJob(5,  mop_w,   wtMop,   512, 512,  512,  512,  0,    1, 0);
  setJob(6,  dout_w,  wtDout,  512, 512,  512,  512,  0,    1, 0);
  setJob(7,  pout_w,  wtPout,  512, 512,  512,  512,  0,    1, 0);
  setJob(8,  geglu_w, wtGeglu, 512, 2048, 2048, 4096, 0,    2, 0);  // a-half
  setJob(9,  geglu_w, wtGeglu, 512, 2048, 2048, 4096, 2048, 2, 1);  // gate-half
  setJob(10, dense_w, wtDense, 2048, 512, 512,  512,  0,    1, 0);
  transpose_all<<<J.tileStart[11], dim3(32, 8), 0, stream>>>(J);

  dim3 tb(32, 8);
  gn_partial<<<512, 256, 0, stream>>>(x, stats);
  gn_apply_t<<<dim3(128, 16, 4), tb, 0, stream>>>(x, stats, gn_g, gn_b, xnt);

  // t = xnt @ pin + b   (fp32 trunk)
  gemm_bt<float, float, 0><<<dim3(4, 128), 512, 0, stream>>>(
      xnt, wtPin, pin_b, nullptr, t32, nullptr, M_, 512, 512);
  // q = LN1(t)
  layernorm_k<<<4096, 256, 0, stream>>>(t32, ln1_g, ln1_b, q16);
  // fused: value = q @ vproj (bf16) ; sa = q @ [soff|attw] (fp32)
  gemm_bt<bf16, float, 4><<<dim3(6, 128), 512, 0, stream>>>(
      q16, wtBig, biasBig, nullptr, v16, sa32, M_, 768, 512);
  // v2 = value @ mvp
  gemm_bt<bf16, float, 0><<<dim3(4, 128), 512, 0, stream>>>(
      v16, wtMvp, mvp_b, nullptr, v2b, nullptr, M_, 512, 512);
  msda_k<<<32768, 256, 0, stream>>>(sa32, v2b, msda);
  // m2 = msda @ mop + b + q ; t2 = m2 @ dout + b + t (fp32 trunk)
  gemm_bt<bf16, bf16, 1><<<dim3(4, 128), 512, 0, stream>>>(
      msda, wtMop, mop_b, q16, m2, nullptr, M_, 512, 512);
  gemm_bt<float, float, 1><<<dim3(4, 128), 512, 0, stream>>>(
      m2, wtDout, dout_b, t32, t2, nullptr, M_, 512, 512);
  // hn = LN3(t2)
  layernorm_k<<<4096, 256, 0, stream>>>(t2, ln3_g, ln3_b, hn);
  // ffin = (hn @ Wa + ba) * gelu(hn @ Wg + bg) — 256^2 4-phase GEGLU, N=4096
  gemm_geglu8<<<dim3(16, 64), 512, 0, stream>>>(hn, wtGeglu, geglu_b, ffin, 512);
  // t3 = ffin @ dense + b + t2
  gemm_bt<bf16, float, 1><<<dim3(4, 128), 512, 0, stream>>>(
      ffin, wtDense, dense_b, t2, t3, nullptr, M_, 512, 2048);
  // out[b,c,l] = (t3 @ pout + b)[b,l,c] + x[b,c,l]   (fused transpose epilogue)
  gemm_bt<float, float, 3><<<dim3(4, 128), 512, 0, stream>>>(
      t3, wtPout, pout_b, x, out, nullptr, M_, 512, 512);
}

// Round 5
// 483.109 us; speedup vs baseline: 1.1609x; 1.0549x over previous
//
#include <hip/hip_runtime.h>
#include <hip/hip_bf16.h>
#include <math.h>

using bf16 = __hip_bfloat16;
typedef __attribute__((ext_vector_type(8))) short short8;
typedef __attribute__((ext_vector_type(4))) float f32x4;

static constexpr int B_ = 4, C_ = 512, L_ = 4096, M_ = 16384;
static constexpr size_t MB = 1ull << 20;

__device__ __forceinline__ float b2f(bf16 v){ return __bfloat162float(v); }
__device__ __forceinline__ bf16  f2b(float v){ return __float2bfloat16(v); }

// async global -> LDS, 16B per lane, lane l lands at (wave-uniform base) + l*16
__device__ __forceinline__ void gl_lds16(const bf16* g, bf16* l) {
  __builtin_amdgcn_global_load_lds(
      (const __attribute__((address_space(1))) unsigned int*)g,
      (__attribute__((address_space(3))) unsigned int*)l, 16, 0, 0);
}

// gelu(g) = 0.5 g (1 + erf(g/sqrt2)); erf via A&S 7.1.26 (|eps| < 1.5e-7)
__device__ __forceinline__ float fast_gelu(float g) {
  float t  = g * 0.70710678118654752f;
  float at = fabsf(t);
  float k  = 1.f / (1.f + 0.3275911f * at);
  float poly = k * (0.254829592f + k * (-0.284496736f + k * (1.421413741f +
               k * (-1.453152027f + k * 1.061405429f))));
  float erfv = 1.f - poly * __expf(-at * at);
  erfv = __builtin_copysignf(erfv, t);
  return 0.5f * g * (1.f + erfv);
}

// ---------------- fused weight transpose: 11 jobs in one dispatch ----------
// mode a==1: dst row = n + b.  mode a==2: granule-16 geglu interleave:
//   dst row = ((n>>4)<<5) + b*16 + (n&15)   (b=0: a-half, b=1: gate-half)
struct TransJobs {
  const float* src[11];
  bf16* dst[11];
  int K[11], N[11], srcStride[11], srcColOff[11], a[11], b[11];
  int tileStart[12];
};

__global__ __launch_bounds__(256) void transpose_all(TransJobs J)
{
  __shared__ float tile[32][33];
  int t = blockIdx.x;
  int j = 0;
  #pragma unroll
  for (int q = 0; q < 10; q++) if (t >= J.tileStart[q + 1]) j = q + 1;
  t -= J.tileStart[j];
  const int kTiles = J.K[j] >> 5;
  const int k0 = (t % kTiles) * 32, n0 = (t / kTiles) * 32;
  const int tx = threadIdx.x, ty = threadIdx.y;
  const float* src = J.src[j];
  const int N = J.N[j], ss = J.srcStride[j], sc = J.srcColOff[j];
  #pragma unroll
  for (int i = 0; i < 32; i += 8) {
    int k = k0 + ty + i, n = n0 + tx;
    tile[ty + i][tx] = (n < N) ? src[(size_t)k * ss + sc + n] : 0.f;
  }
  __syncthreads();
  bf16* dst = J.dst[j];
  const int a = J.a[j], b = J.b[j], K = J.K[j];
  #pragma unroll
  for (int i = 0; i < 32; i += 8) {
    int n = n0 + ty + i, k = k0 + tx;
    int row = (a == 2) ? (((n >> 4) << 5) + b * 16 + (n & 15)) : (n + b);
    dst[(size_t)row * K + k] = f2b(tile[tx][ty + i]);
  }
}

// combined bias [vproj(512) | soff(128) | attw(64) | zero(64)]
__global__ void pack_bias_big(const float* __restrict__ vb,
    const float* __restrict__ sb, const float* __restrict__ ab,
    float* __restrict__ bp){
  int i = blockIdx.x * 256 + threadIdx.x;   // 768 threads
  float v = 0.f;
  if (i < 512) v = vb[i];
  else if (i < 640) v = sb[i - 512];
  else if (i < 704) v = ab[i - 640];
  bp[i] = v;
}

// ---------------- GroupNorm stats (sum, sumsq per (b,g)) ----------------
__global__ __launch_bounds__(256) void gn_partial(const float* __restrict__ x,
                                                  float* __restrict__ stats)
{
  int bg = blockIdx.x >> 4;
  int sc = blockIdx.x & 15;
  size_t base = (size_t)bg * 262144 + (size_t)sc * 16384;
  int tid = threadIdx.x;
  float s = 0.f, s2 = 0.f;
  #pragma unroll
  for (int i = 0; i < 8; i++) {
    size_t o = base + ((size_t)i * 256 + tid) * 8;
    float4 a = *reinterpret_cast<const float4*>(&x[o]);
    float4 b = *reinterpret_cast<const float4*>(&x[o + 4]);
    s  += a.x + a.y + a.z + a.w + b.x + b.y + b.z + b.w;
    s2 += a.x*a.x + a.y*a.y + a.z*a.z + a.w*a.w
        + b.x*b.x + b.y*b.y + b.z*b.z + b.w*b.w;
  }
  #pragma unroll
  for (int o = 32; o; o >>= 1) { s += __shfl_xor(s, o, 64); s2 += __shfl_xor(s2, o, 64); }
  __shared__ float ls[4], ls2[4];
  int wave = tid >> 6, lane = tid & 63;
  if (lane == 0) { ls[wave] = s; ls2[wave] = s2; }
  __syncthreads();
  if (tid == 0) {
    atomicAdd(&stats[bg * 2 + 0], ls[0] + ls[1] + ls[2] + ls[3]);
    atomicAdd(&stats[bg * 2 + 1], ls2[0] + ls2[1] + ls2[2] + ls2[3]);
  }
}

// ---------------- GN apply + transpose (B,C,L) -> (B*L, C) bf16 ----------
__global__ __launch_bounds__(256) void gn_apply_t(const float* __restrict__ x,
    const float* __restrict__ stats, const float* __restrict__ gg,
    const float* __restrict__ gb, bf16* __restrict__ xnt)
{
  __shared__ float tile[32][33];
  int b = blockIdx.z, c0 = blockIdx.y * 32, l0 = blockIdx.x * 32;
  int tx = threadIdx.x, ty = threadIdx.y;
  #pragma unroll
  for (int i = 0; i < 32; i += 8) {
    int c = c0 + ty + i, l = l0 + tx;
    int grp = b * 8 + (c >> 6);
    float sum = stats[grp * 2], ss = stats[grp * 2 + 1];
    float mu = sum * (1.f / 262144.f);
    float inv = rsqrtf(ss * (1.f / 262144.f) - mu * mu + 1e-5f);
    float v = x[((size_t)b * 512 + c) * 4096 + l];
    tile[ty + i][tx] = (v - mu) * inv * gg[c] + gb[c];
  }
  __syncthreads();
  #pragma unroll
  for (int i = 0; i < 32; i += 8) {
    int l = l0 + ty + i, c = c0 + tx;
    xnt[((size_t)b * 4096 + l) * 512 + c] = f2b(tile[tx][ty + i]);
  }
}

// ---------------- LayerNorm over C=512: bf16 in, bf16 out, 1 wave/row -----
__global__ __launch_bounds__(256) void layernorm_b(const bf16* __restrict__ X,
    const float* __restrict__ g, const float* __restrict__ b, bf16* __restrict__ Y)
{
  int row = blockIdx.x * 4 + (threadIdx.x >> 6);
  int lane = threadIdx.x & 63;
  const bf16* xr = X + (size_t)row * 512 + lane * 8;
  short8 rv = *reinterpret_cast<const short8*>(xr);
  float v[8];
  #pragma unroll
  for (int i = 0; i < 8; i++)
    v[i] = __uint_as_float((unsigned)(unsigned short)rv[i] << 16);
  float s = 0.f, s2 = 0.f;
  #pragma unroll
  for (int i = 0; i < 8; i++) { s += v[i]; s2 += v[i] * v[i]; }
  #pragma unroll
  for (int o = 32; o; o >>= 1) { s += __shfl_xor(s, o, 64); s2 += __shfl_xor(s2, o, 64); }
  float mu = s * (1.f / 512.f);
  float inv = rsqrtf(s2 * (1.f / 512.f) - mu * mu + 1e-5f);
  float4 g0 = *reinterpret_cast<const float4*>(&g[lane * 8]);
  float4 g1 = *reinterpret_cast<const float4*>(&g[lane * 8 + 4]);
  float4 b0 = *reinterpret_cast<const float4*>(&b[lane * 8]);
  float4 b1 = *reinterpret_cast<const float4*>(&b[lane * 8 + 4]);
  float gv[8] = {g0.x, g0.y, g0.z, g0.w, g1.x, g1.y, g1.z, g1.w};
  float bv[8] = {b0.x, b0.y, b0.z, b0.w, b1.x, b1.y, b1.z, b1.w};
  bf16 outv[8];
  #pragma unroll
  for (int i = 0; i < 8; i++) outv[i] = f2b((v[i] - mu) * inv * gv[i] + bv[i]);
  *reinterpret_cast<uint4*>(Y + (size_t)row * 512 + lane * 8) =
      *reinterpret_cast<const uint4*>(outv);
}

// --- MFMA GEMM, 128x128 tile, 512 threads (8 waves, 2x4 frags/wave) -------
// BK=64 full-line staging + XOR swizzle, dbuf. LDS 64 KB -> 2 blocks/CU,
// 16 waves/CU = 4 waves/SIMD. XCD-contiguous block swizzle (round-3):
// remap hw -> (hw&7)*(nwg/8)+hw>>3 (bijective, all grids %8==0): each XCD
// owns contiguous logical blocks = whole m-panels with all their n-blocks.
// EPI: 0 none | 1 += res[idx] | 3 transpose+residual fp32 out
// EPI 4: n0<512 -> bf16 Cv[m*512+n]; n0>=512 -> fp32 out2[m*256+n-512]
template<typename TOUT, typename TRES, int EPI>
__global__ __launch_bounds__(512) void gemm_bt(const bf16* __restrict__ A,
    const bf16* __restrict__ Bt, const float* __restrict__ bias,
    const TRES* __restrict__ res, TOUT* __restrict__ Cv,
    float* __restrict__ out2, int M, int N, int K)
{
  __shared__ alignas(16) bf16 As[2][128 * 64];
  __shared__ alignas(16) bf16 Bs[2][128 * 64];
  const int tid = threadIdx.x;
  const int gx = gridDim.x;
  const int nwg = gx * gridDim.y;
  int hw = blockIdx.y * gx + blockIdx.x;
  int lg = (hw & 7) * (nwg >> 3) + (hw >> 3);    // nwg % 8 == 0 for all grids
  const int m0 = (lg / gx) * 128;
  const int n0 = (lg % gx) * 128;
  const int lane = tid & 63;
  const int wave = tid >> 6;            // 0..7
  const int wm = (wave & 3) * 32;       // 4 m-strips of 32 rows
  const int wn = (wave >> 2) * 64;      // 2 n-strips of 64 cols
  const int fr = lane & 15;
  const int fq = lane >> 4;
  const int sr8 = lane >> 3;                    // row within 8-row staging group
  const int sgl = ((lane & 7) ^ sr8) * 8;       // swizzled source granule (elems)

  const bf16* gaBase = A  + (size_t)(m0 + wave * 16 + sr8) * K + sgl;
  const bf16* gbBase = Bt + (size_t)(n0 + wave * 16 + sr8) * K + sgl;

  f32x4 acc[2][4];
  #pragma unroll
  for (int i = 0; i < 2; i++)
    #pragma unroll
    for (int j = 0; j < 4; j++) acc[i][j] = (f32x4){0.f, 0.f, 0.f, 0.f};

  auto stage = [&](int buf, int kt) {
    const bf16* ga = gaBase + kt;
    const bf16* gb = gbBase + kt;
    bf16* la = &As[buf][wave * 16 * 64];
    bf16* lb = &Bs[buf][wave * 16 * 64];
    gl_lds16(ga, la);                    gl_lds16(ga + (size_t)8 * K, la + 8 * 64);
    gl_lds16(gb, lb);                    gl_lds16(gb + (size_t)8 * K, lb + 8 * 64);
  };

  stage(0, 0);
  int cur = 0;
  for (int kt = 0; kt < K; kt += 64) {
    __syncthreads();                            // drains stage(cur)
    if (kt + 64 < K) stage(cur ^ 1, kt + 64);   // async prefetch next tile
    #pragma unroll
    for (int ko = 0; ko < 2; ko++) {
      const int pa = ((ko * 4 + fq) ^ (fr & 7)) * 8;
      short8 af[2], bfv[4];
      #pragma unroll
      for (int mi = 0; mi < 2; mi++)
        af[mi] = *reinterpret_cast<const short8*>(&As[cur][(wm + mi * 16 + fr) * 64 + pa]);
      #pragma unroll
      for (int ni = 0; ni < 4; ni++)
        bfv[ni] = *reinterpret_cast<const short8*>(&Bs[cur][(wn + ni * 16 + fr) * 64 + pa]);
      #pragma unroll
      for (int mi = 0; mi < 2; mi++)
        #pragma unroll
        for (int ni = 0; ni < 4; ni++)
          acc[mi][ni] = __builtin_amdgcn_mfma_f32_16x16x32_bf16(af[mi], bfv[ni],
                                                                acc[mi][ni], 0, 0, 0);
    }
    cur ^= 1;
  }

  // epilogue: C/D layout col = lane&15, row = (lane>>4)*4 + reg
  #pragma unroll
  for (int ni = 0; ni < 4; ni++) {
    int n = n0 + wn + ni * 16 + fr;
    float bv = bias[n];
    #pragma unroll
    for (int mi = 0; mi < 2; mi++) {
      int mbase = m0 + wm + mi * 16 + fq * 4;
      if (EPI == 3) {
        int b = mbase >> 12, l = mbase & 4095;
        size_t o = ((size_t)(b * 512 + n) << 12) + l;
        float4 xr = *reinterpret_cast<const float4*>(&((const float*)res)[o]);
        float4 vv;
        vv.x = acc[mi][ni][0] + bv + xr.x;
        vv.y = acc[mi][ni][1] + bv + xr.y;
        vv.z = acc[mi][ni][2] + bv + xr.z;
        vv.w = acc[mi][ni][3] + bv + xr.w;
        *reinterpret_cast<float4*>(&((float*)Cv)[o]) = vv;
      } else if (EPI == 4) {
        #pragma unroll
        for (int r = 0; r < 4; r++) {
          float v = acc[mi][ni][r] + bv;
          if (n0 < 512) ((bf16*)Cv)[(size_t)(mbase + r) * 512 + n] = f2b(v);
          else          out2[(size_t)(mbase + r) * 256 + (n - 512)] = v;
        }
      } else {
        #pragma unroll
        for (int r = 0; r < 4; r++) {
          size_t idx = (size_t)(mbase + r) * N + n;
          float v = acc[mi][ni][r] + bv;
          if (EPI == 1) {
            float rv;
            if constexpr (sizeof(TRES) == 2) rv = b2f(((const bf16*)res)[idx]);
            else                             rv = ((const float*)res)[idx];
            v += rv;
          }
          if constexpr (sizeof(TOUT) == 2) ((bf16*)Cv)[idx] = f2b(v);
          else                             ((float*)Cv)[idx] = v;
        }
      }
    }
  }
}

// ====================== GEGLU GEMM — 256x256, 4-phase/2-tile schedule =====
// (Round-2 verified version; structural ~640 TF wall for K=512, parked.)
#define GG_BAR() __builtin_amdgcn_s_barrier()
#define GG_LG0() do { asm volatile("s_waitcnt lgkmcnt(0)" ::: "memory"); \
                      __builtin_amdgcn_sched_barrier(0); } while (0)
#define GG_VM4() do { asm volatile("s_waitcnt vmcnt(4)" ::: "memory"); \
                      __builtin_amdgcn_sched_barrier(0); } while (0)

#define GG_READ_A(BUF, S)                                                      \
  {                                                                            \
    _Pragma("unroll") for (int mi = 0; mi < 2; mi++)                           \
      _Pragma("unroll") for (int ko = 0; ko < 2; ko++) {                       \
        const int row = wm * 128 + ((S) * 2 + mi) * 16 + fr;                   \
        const int pa = ((ko * 4 + fq) ^ (fr & 7)) * 8;                         \
        af[mi][ko] = *reinterpret_cast<const short8*>(&As[BUF][row * 64 + pa]);\
      }                                                                        \
  }

#define GG_READ_B(BUF)                                                         \
  {                                                                            \
    _Pragma("unroll") for (int ni = 0; ni < 4; ni++)                           \
      _Pragma("unroll") for (int ko = 0; ko < 2; ko++) {                       \
        const int row = wn + ni * 16 + fr;                                     \
        const int pa = ((ko * 4 + fq) ^ (fr & 7)) * 8;                         \
        bfv[ni][ko] = *reinterpret_cast<const short8*>(&Bs[BUF][row * 64 + pa]); \
      }                                                                        \
  }

#define GG_MFMA(S)                                                             \
  __builtin_amdgcn_s_setprio(1);                                               \
  _Pragma("unroll") for (int mi = 0; mi < 2; mi++)                             \
    _Pragma("unroll") for (int ni = 0; ni < 4; ni++)                           \
      _Pragma("unroll") for (int ko = 0; ko < 2; ko++)                         \
        acc[(S) * 2 + mi][ni] = __builtin_amdgcn_mfma_f32_16x16x32_bf16(       \
            af[mi][ko], bfv[ni][ko], acc[(S) * 2 + mi][ni], 0, 0, 0);          \
  __builtin_amdgcn_s_setprio(0);

// one barrier-pair phase: strips S0,S0+1 of buf BUF; STAGE issued pre-bar
#define GG_PHASE(BUF, S0, STAGE_CODE, DO_VM)                                   \
  GG_READ_A(BUF, S0);                                                          \
  if ((S0) == 0) { GG_READ_B(BUF); }                                           \
  STAGE_CODE;                                                                  \
  GG_BAR();                                                                    \
  GG_LG0();                                                                    \
  GG_MFMA(S0);                                                                 \
  GG_READ_A(BUF, (S0) + 1);                                                    \
  GG_LG0();                                                                    \
  GG_MFMA((S0) + 1);                                                           \
  if (DO_VM) { GG_VM4(); }                                                     \
  GG_BAR();

__global__ __launch_bounds__(512, 2) void gemm_geglu8(const bf16* __restrict__ A,
    const bf16* __restrict__ Wt, const float* __restrict__ gb,
    bf16* __restrict__ Cv, int K)
{
  __shared__ alignas(16) bf16 As[2][256 * 64];
  __shared__ alignas(16) bf16 Bs[2][256 * 64];
  const int tid = threadIdx.x;
  // bijective XCD swizzle for grid (16,64): XCD k gets 8 contiguous m-panels
  int bid = blockIdx.y * 16 + blockIdx.x;        // 1024 blocks, 1024%8==0
  bid = (bid & 7) * 128 + (bid >> 3);
  const int m0 = (bid >> 4) * 256;
  const int n0 = (bid & 15) * 256;               // interleaved-row space
  const int lane = tid & 63;
  const int wave = tid >> 6;             // 0..7
  const int wm = wave >> 2;              // 0..1 -> 128-row half of M-tile
  const int wn = (wave & 3) * 64;        // 4 strips of 64 interleaved cols
  const int fr = lane & 15;
  const int fq = lane >> 4;
  const int sr8 = lane >> 3;                    // row within 8-row staging group
  const int sgl = ((lane & 7) ^ sr8) * 8;       // swizzled source granule (elems)

  // staging: wave w covers rows half*128 + w*16 + {sr8, sr8+8}
  const bf16* gaB = A  + (size_t)(m0 + wave * 16 + sr8) * K + sgl;
  const bf16* gbB = Wt + (size_t)(n0 + wave * 16 + sr8) * K + sgl;

  auto stageA = [&](int buf, int half, int kt) {
    const bf16* g = gaB + (size_t)(half * 128) * K + kt;
    bf16* l = &As[buf][(half * 128 + wave * 16) * 64];
    gl_lds16(g, l);  gl_lds16(g + (size_t)8 * K, l + 8 * 64);
  };
  auto stageB = [&](int buf, int half, int kt) {
    const bf16* g = gbB + (size_t)(half * 128) * K + kt;
    bf16* l = &Bs[buf][(half * 128 + wave * 16) * 64];
    gl_lds16(g, l);  gl_lds16(g + (size_t)8 * K, l + 8 * 64);
  };

  f32x4 acc[8][4];
  #pragma unroll
  for (int i = 0; i < 8; i++)
    #pragma unroll
    for (int j = 0; j < 4; j++) acc[i][j] = (f32x4){0.f, 0.f, 0.f, 0.f};

  // prologue: tile0 A+B, tile1 B (12 loads); wait oldest 8 (tile0 complete)
  stageA(0, 0, 0); stageA(0, 1, 0); stageB(0, 0, 0); stageB(0, 1, 0);
  stageB(1, 0, 64); stageB(1, 1, 64);
  GG_VM4();
  GG_BAR();

  short8 af[2][2];
  short8 bfv[4][2];
  for (int t0 = 0; t0 < K; t0 += 128) {
    const int kA1 = t0 + 64;                       // always < K (K%128==0)
    int kN2 = t0 + 128; if (kN2 >= K) kN2 = 0;     // dummy re-stage on tail
    int kN3 = t0 + 192; if (kN3 >= K) kN3 = 0;
    // alpha: tile T (buf0) strips 0-1; stage A(T+1) -> As[1]
    GG_PHASE(0, 0, { stageA(1, 0, kA1); stageA(1, 1, kA1); }, false)
    // beta: tile T strips 2-3; stage B(T+2) -> Bs[0]; VM4 drains A/B(T+1)
    GG_PHASE(0, 2, { stageB(0, 0, kN2); stageB(0, 1, kN2); }, true)
    // gamma: tile T+1 (buf1) strips 0-1; stage A(T+2) -> As[0]
    GG_PHASE(1, 0, { stageA(0, 0, kN2); stageA(0, 1, kN2); }, false)
    // delta: tile T+1 strips 2-3; stage B(T+3) -> Bs[1]; VM4 drains A/B(T+2)
    GG_PHASE(1, 2, { stageB(1, 0, kN3); stageB(1, 1, kN3); }, true)
  }

  // epilogue: n-frags pair up as (a, gate) per 16-col granule
  const int cbase = (n0 + wn) >> 1;
  #pragma unroll
  for (int pi = 0; pi < 2; pi++) {
    int col = cbase + pi * 16 + fr;
    float ba = gb[col];
    float bg = gb[2048 + col];
    #pragma unroll
    for (int mi = 0; mi < 8; mi++) {
      int mbase = m0 + wm * 128 + mi * 16 + fq * 4;
      #pragma unroll
      for (int r = 0; r < 4; r++) {
        float a = acc[mi][2 * pi][r] + ba;
        float g = acc[mi][2 * pi + 1][r] + bg;
        Cv[(size_t)(mbase + r) * 2048 + col] = f2b(a * fast_gelu(g));
      }
    }
  }
}

// ---------------- MSDA: degenerate deformable attention (Hl=L, Wl=1) ------
// sa: [M][256] fp32: cols 0..127 = sampling offsets, 128..191 = attn logits
__global__ __launch_bounds__(256) void msda_k(const float* __restrict__ sa,
    const bf16* __restrict__ v2, bf16* __restrict__ outp)
{
  int unit = blockIdx.x * 4 + (threadIdx.x >> 6);  // (b*L+l)*8 + h
  int lane = threadIdx.x & 63;
  int m = unit >> 3;
  int h = unit & 7;
  int b = m >> 12;                                  // L = 4096
  const float* lg = &sa[(size_t)m * 256 + 128 + h * 8];
  float w[8], mx = -1e30f;
  #pragma unroll
  for (int p = 0; p < 8; p++) { w[p] = lg[p]; mx = fmaxf(mx, w[p]); }
  float sum = 0.f;
  #pragma unroll
  for (int p = 0; p < 8; p++) { w[p] = expf(w[p] - mx); sum += w[p]; }
  float rs = 1.f / sum;
  const float* op = &sa[(size_t)m * 256 + h * 16];
  size_t vbase = ((size_t)b * 4096) * 512 + h * 64 + lane;
  float acc = 0.f;
  #pragma unroll
  for (int p = 0; p < 8; p++) {
    float ox = op[p * 2 + 0], oy = op[p * 2 + 1];
    float gx = 2.f * (0.5f + ox) - 1.f;
    float px = ((gx + 1.f) * 1.f - 1.f) * 0.5f;              // = ox (mirrors ref fp ops)
    float gy = 2.f * (0.5f + oy * (1.f / 4096.f)) - 1.f;
    float py = ((gy + 1.f) * 4096.f - 1.f) * 0.5f;           // = oy + 2047.5
    float x0 = floorf(px), y0 = floorf(py);
    float lx = px - x0, ly = py - y0;
    int xi = (int)x0;
    int yi = (int)y0;
    float wx = (xi == 0) ? (1.f - lx) : ((xi == -1) ? lx : 0.f);
    if (wx != 0.f) {                         // wave-uniform branch
      float s = 0.f;
      if (yi >= 0 && yi < 4096)  s += (1.f - ly) * b2f(v2[vbase + (size_t)yi * 512]);
      if (yi >= -1 && yi < 4095) s += ly * b2f(v2[vbase + (size_t)(yi + 1) * 512]);
      acc += w[p] * rs * wx * s;
    }
  }
  outp[(size_t)m * 512 + h * 64 + lane] = f2b(acc);
}

// =========================================================================
extern "C" void kernel_launch(void* const* d_in, const int* in_sizes, int n_in,
                              void* d_out, int out_size, void* d_ws, size_t ws_size,
                              hipStream_t stream)
{
  if (n_in < 27) return;
  const float* x       = (const float*)d_in[0];
  const float* gn_g    = (const float*)d_in[1];
  const float* gn_b    = (const float*)d_in[2];
  const float* pin_w   = (const float*)d_in[3];
  const float* pin_b   = (const float*)d_in[4];
  const float* ln1_g   = (const float*)d_in[5];
  const float* ln1_b   = (const float*)d_in[6];
  const float* vproj_w = (const float*)d_in[7];
  const float* vproj_b = (const float*)d_in[8];
  const float* mvp_w   = (const float*)d_in[9];
  const float* mvp_b   = (const float*)d_in[10];
  const float* soff_w  = (const float*)d_in[11];
  const float* soff_b  = (const float*)d_in[12];
  const float* attw_w  = (const float*)d_in[13];
  const float* attw_b  = (const float*)d_in[14];
  const float* mop_w   = (const float*)d_in[15];
  const float* mop_b   = (const float*)d_in[16];
  const float* dout_w  = (const float*)d_in[17];
  const float* dout_b  = (const float*)d_in[18];
  const float* ln3_g   = (const float*)d_in[19];
  const float* ln3_b   = (const float*)d_in[20];
  const float* geglu_w = (const float*)d_in[21];
  const float* geglu_b = (const float*)d_in[22];
  const float* dense_w = (const float*)d_in[23];
  const float* dense_b = (const float*)d_in[24];
  const float* pout_w  = (const float*)d_in[25];
  const float* pout_b  = (const float*)d_in[26];
  float* out = (float*)d_out;

  char* ws = (char*)d_ws;
  size_t off = 0;
  auto alloc = [&](size_t bytes) -> char* {
    off = (off + 255) & ~(size_t)255;
    char* p = ws + off;
    off += bytes;
    return p;
  };
  // persistent weights (bf16, transposed)
  bf16* wtPin   = (bf16*)alloc(512 * 512 * 2);
  bf16* wtBig   = (bf16*)alloc(768 * 512 * 2);     // [vproj 512 | soff 128 | attw 64 | pad 64]
  bf16* wtMvp   = (bf16*)alloc(512 * 512 * 2);
  bf16* wtMop   = (bf16*)alloc(512 * 512 * 2);
  bf16* wtDout  = (bf16*)alloc(512 * 512 * 2);
  bf16* wtPout  = (bf16*)alloc(512 * 512 * 2);
  bf16* wtGeglu = (bf16*)alloc((size_t)4096 * 512 * 2);   // granule-16 interleaved
  bf16* wtDense = (bf16*)alloc((size_t)512 * 2048 * 2);
  float* biasBig = (float*)alloc(768 * 4);
  float* stats   = (float*)alloc(64 * 4);
  // activation regions with liveness-checked unions (bf16 trunk, round-5)
  char* A  = alloc(32 * MB);  // t16@0 (16MB, dead after dout) | hn@0 ; t3@16MB
  char* Cg = alloc(32 * MB);  // t2b (bf16, 16MB)
  char* D  = alloc(64 * MB);  // xnt@0, v@16, v2@32, msda@48
  char* E  = alloc(64 * MB);  // q16@0, sa32@16 (16MB), m2@32 (16MB) | ffin@0 (64MB)
  if (off > ws_size) return;  // workspace too small — fail loudly (zero output)

  bf16*  t16   = (bf16*)A;
  bf16*  hn    = (bf16*)A;
  bf16*  t3    = (bf16*)(A + 16 * MB);
  bf16*  t2b   = (bf16*)Cg;
  bf16*  xnt   = (bf16*)D;
  bf16*  v16   = (bf16*)(D + 16 * MB);
  bf16*  v2b   = (bf16*)(D + 32 * MB);
  bf16*  msda  = (bf16*)(D + 48 * MB);
  bf16*  q16   = (bf16*)E;
  float* sa32  = (float*)(E + 16 * MB);
  bf16*  m2    = (bf16*)(E + 32 * MB);
  bf16*  ffin  = (bf16*)E;

  hipMemsetAsync(stats, 0, 64 * 4, stream);
  pack_bias_big<<<3, 256, 0, stream>>>(vproj_b, soff_b, attw_b, biasBig);

  // fused transpose: 11 jobs
  TransJobs J{};
  auto setJob = [&](int j, const float* src, bf16* dst, int K, int N, int Npad,
                    int ss, int sc, int a, int b) {
    J.src[j] = src; J.dst[j] = dst; J.K[j] = K; J.N[j] = N;
    J.srcStride[j] = ss; J.srcColOff[j] = sc; J.a[j] = a; J.b[j] = b;
    J.tileStart[j + 1] = J.tileStart[j] + (K / 32) * (Npad / 32);
  };
  J.tileStart[0] = 0;
  setJob(0,  pin_w,   wtPin,   512, 512,  512,  512,  0,    1, 0);
  setJob(1,  vproj_w, wtBig,   512, 512,  512,  512,  0,    1, 0);
  setJob(2,  soff_w,  wtBig,   512, 128,  128,  128,  0,    1, 512);
  setJob(3,  attw_w,  wtBig,   512, 64,   128,  64,   0,    1, 640);
  setJob(4,  mvp_w,   wtMvp,   512, 512,  512,  512,  0,    1, 0);
  setJob(5,  mop_w,   wtMop,   512, 512,  512,  512,  0,    1, 0);
  setJob(6,  dout_w,  wtDout,  512, 512,  512,  512,  0,    1, 0);
  setJob(7,  pout_w,  wtPout,  512, 512,  512,  512,  0,    1, 0);
  setJob(8,  geglu_w, wtGeglu, 512, 2048, 2048, 4096, 0,    2, 0);  // a-half
  setJob(9,  geglu_w, wtGeglu, 512, 2048, 2048, 4096, 2048, 2, 1);  // gate-half
  setJob(10, dense_w, wtDense, 2048, 512, 512,  512,  0,    1, 0);
  transpose_all<<<J.tileStart[11], dim3(32, 8), 0, stream>>>(J);

  dim3 tb(32, 8);
  gn_partial<<<512, 256, 0, stream>>>(x, stats);
  gn_apply_t<<<dim3(128, 16, 4), tb, 0, stream>>>(x, stats, gn_g, gn_b, xnt);

  // t = xnt @ pin + b   (bf16 trunk, round-5)
  gemm_bt<bf16, float, 0><<<dim3(4, 128), 512, 0, stream>>>(
      xnt, wtPin, pin_b, nullptr, t16, nullptr, M_, 512, 512);
  // q = LN1(t)
  layernorm_b<<<4096, 256, 0, stream>>>(t16, ln1_g, ln1_b, q16);
  // fused: value = q @ vproj (bf16) ; sa = q @ [soff|attw] (fp32)
  gemm_bt<bf16, float, 4><<<dim3(6, 128), 512, 0, stream>>>(
      q16, wtBig, biasBig, nullptr, v16, sa32, M_, 768, 512);
  // v2 = value @ mvp
  gemm_bt<bf16, float, 0><<<dim3(4, 128), 512, 0, stream>>>(
      v16, wtMvp, mvp_b, nullptr, v2b, nullptr, M_, 512, 512);
  msda_k<<<32768, 256, 0, stream>>>(sa32, v2b, msda);
  // m2 = msda @ mop + b + q ; t2 = m2 @ dout + b + t (bf16 trunk)
  gemm_bt<bf16, bf16, 1><<<dim3(4, 128), 512, 0, stream>>>(
      msda, wtMop, mop_b, q16, m2, nullptr, M_, 512, 512);
  gemm_bt<bf16, bf16, 1><<<dim3(4, 128), 512, 0, stream>>>(
      m2, wtDout, dout_b, t16, t2b, nullptr, M_, 512, 512);
  // hn = LN3(t2)
  layernorm_b<<<4096, 256, 0, stream>>>(t2b, ln3_g, ln3_b, hn);
  // ffin = (hn @ Wa + ba) * gelu(hn @ Wg + bg) — 256^2 4-phase GEGLU, N=4096
  gemm_geglu8<<<dim3(16, 64), 512, 0, stream>>>(hn, wtGeglu, geglu_b, ffin, 512);
  // t3 = ffin @ dense + b + t2
  gemm_bt<bf16, bf16, 1><<<dim3(4, 128), 512, 0, stream>>>(
      ffin, wtDense, dense_b, t2b, t3, nullptr, M_, 512, 2048);
  // out[b,c,l] = (t3 @ pout + b)[b,l,c] + x[b,c,l]   (fused transpose epilogue)
  gemm_bt<float, float, 3><<<dim3(4, 128), 512, 0, stream>>>(
      t3, wtPout, pout_b, x, out, nullptr, M_, 512, 512);
}